// Round 13
// baseline (176.424 us; speedup 1.0000x reference)
//
#include <hip/hip_runtime.h>

typedef unsigned int u32;
typedef unsigned char u8;

static __device__ __forceinline__ float leaky(float v) {
    return v >= 0.0f ? v : 0.01f * v;
}

#define P1C 4096
#define NB2 64             // coarse buckets = dst>>11 (requires nN <= 131072)
#define CAP2_LOG 17        // per-bucket capacity 131072; mean load nE*2048/nN
                           // = 102400, sigma ~320 -> +90 sigma headroom
#define ASPL2 16           // sub-blocks per bucket for agg
#define S1F 8388608.0f     // 2^23 fixed-point scale, layer 1
#define S2F 2097152.0f     // 2^21 fixed-point scale, layer 2

// ====== scatter: 64 coarse buckets, wave-scan, block reservation ===========
__global__ __launch_bounds__(256) void k_p1scatterB(
        const int* __restrict__ src, const int* __restrict__ dst,
        int* __restrict__ cur, u32* __restrict__ bkt, int nE) {
    __shared__ int sc[NB2];
    __shared__ int loff[NB2];
    __shared__ int gb[NB2];
    __shared__ int lcur[NB2];
    __shared__ u32 pay[P1C];
    __shared__ u8 bb[P1C];
    int t = threadIdx.x;
    if (t < NB2) sc[t] = 0;
    __syncthreads();
    int base = blockIdx.x * P1C;
    int lim = min(P1C, nE - base);
    if (lim == P1C) {
        const int4* p = (const int4*)(dst + base);
        for (int i = t; i < P1C / 4; i += 256) {
            int4 v = p[i];
            atomicAdd(&sc[v.x >> 11], 1);
            atomicAdd(&sc[v.y >> 11], 1);
            atomicAdd(&sc[v.z >> 11], 1);
            atomicAdd(&sc[v.w >> 11], 1);
        }
    } else {
        for (int i = t; i < lim; i += 256)
            atomicAdd(&sc[dst[base + i] >> 11], 1);
    }
    __syncthreads();
    if (t < NB2) {                         // one wave: reserve + shuffle-scan
        int c = sc[t];
        gb[t] = (t << CAP2_LOG) + ((c > 0) ? atomicAdd(&cur[t], c) : 0);
        int incl = c;
#pragma unroll
        for (int o = 1; o < NB2; o <<= 1) {
            int xv = __shfl_up(incl, o);
            if (t >= o) incl += xv;
        }
        loff[t] = incl - c;
        lcur[t] = incl - c;
    }
    __syncthreads();
    int n4 = lim >> 2;
    const int4* d4p = (const int4*)(dst + base);
    const int4* s4p = (const int4*)(src + base);
    for (int i = t; i < n4; i += 256) {
        int4 d4 = d4p[i];
        int4 s4 = s4p[i];
        int b, r;
        b = d4.x >> 11; r = atomicAdd(&lcur[b], 1);
        pay[r] = (u32)(((d4.x & 2047) << 17) | s4.x); bb[r] = (u8)b;
        b = d4.y >> 11; r = atomicAdd(&lcur[b], 1);
        pay[r] = (u32)(((d4.y & 2047) << 17) | s4.y); bb[r] = (u8)b;
        b = d4.z >> 11; r = atomicAdd(&lcur[b], 1);
        pay[r] = (u32)(((d4.z & 2047) << 17) | s4.z); bb[r] = (u8)b;
        b = d4.w >> 11; r = atomicAdd(&lcur[b], 1);
        pay[r] = (u32)(((d4.w & 2047) << 17) | s4.w); bb[r] = (u8)b;
    }
    for (int i = (n4 << 2) + t; i < lim; i += 256) {
        int d = dst[base + i], s = src[base + i];
        int b = d >> 11;
        int r = atomicAdd(&lcur[b], 1);
        pay[r] = (u32)(((d & 2047) << 17) | s);
        bb[r] = (u8)b;
    }
    __syncthreads();
    for (int i = t; i < lim; i += 256) {
        int b = bb[i];
        bkt[gb[b] + (i - loff[b])] = pay[i];
    }
}

// ====== cnt: per-bucket 2048-bin degree histogram -> dinv + hd0 ============
__global__ __launch_bounds__(256) void k_cntB(
        const u32* __restrict__ bkt, const int* __restrict__ cur,
        const int* __restrict__ x, const float* __restrict__ emb,
        float* __restrict__ dinv, float4* __restrict__ hd0, int nN) {
    __shared__ int h[2048];
    int t = threadIdx.x, b = blockIdx.x;
    for (int k = t; k < 2048; k += 256) h[k] = 0;
    __syncthreads();
    int base = b << CAP2_LOG;
    int end = base + cur[b];
    int vend = base + ((end - base) & ~3);     // base 16B-aligned
    for (int i = base + t * 4; i < vend; i += 1024) {
        uint4 v = *(const uint4*)&bkt[i];
        atomicAdd(&h[v.x >> 17], 1);
        atomicAdd(&h[v.y >> 17], 1);
        atomicAdd(&h[v.z >> 17], 1);
        atomicAdd(&h[v.w >> 17], 1);
    }
    if (vend + t < end) atomicAdd(&h[bkt[vend + t] >> 17], 1);
    __syncthreads();
#pragma unroll
    for (int k = 0; k < 8; ++k) {
        int bin = t + k * 256;
        int d = b * 2048 + bin;
        if (d < nN) {
            float di = rsqrtf((float)h[bin] + 1.0f);
            dinv[d] = di;
            int xi = x[d] * 3;
            hd0[d] = make_float4(emb[xi] * di, emb[xi + 1] * di,
                                 emb[xi + 2] * di, 0.f);
        }
    }
}

// ====== agg: fixed-point LDS accumulation over 2048 bins ===================
__global__ __launch_bounds__(256) void k_aggB(
        const u32* __restrict__ bkt, const int* __restrict__ cur,
        const float4* __restrict__ tab, float* __restrict__ pacc,
        float scale, float inv_scale) {
    __shared__ int acc[6144];
    int t = threadIdx.x;
    int blk = blockIdx.x, b = blk >> 4, s = blk & 15;
    int base = b << CAP2_LOG;
    int sz = cur[b];
    int chunk = (sz + ASPL2 - 1) / ASPL2;
    int st = min(base + s * chunk, base + sz);
    int en = min(st + chunk, base + sz);
    for (int k = t; k < 6144; k += 256) acc[k] = 0;
    __syncthreads();
    int a0 = min((st + 3) & ~3, en);
    if (st + t < a0) {
        u32 v = bkt[st + t];
        float4 h = tab[v & 0x1FFFFu];
        int bin = (int)(v >> 17) * 3;
        atomicAdd(&acc[bin + 0], __float2int_rn(h.x * scale));
        atomicAdd(&acc[bin + 1], __float2int_rn(h.y * scale));
        atomicAdd(&acc[bin + 2], __float2int_rn(h.z * scale));
    }
    int vend = a0 + ((en - a0) & ~3);
    for (int i = a0 + t * 4; i < vend; i += 1024) {
        uint4 v = *(const uint4*)&bkt[i];
        float4 h0 = tab[v.x & 0x1FFFFu];
        float4 h1 = tab[v.y & 0x1FFFFu];
        float4 h2 = tab[v.z & 0x1FFFFu];
        float4 h3 = tab[v.w & 0x1FFFFu];
        int b0 = (int)(v.x >> 17) * 3, b1 = (int)(v.y >> 17) * 3;
        int b2 = (int)(v.z >> 17) * 3, b3 = (int)(v.w >> 17) * 3;
        atomicAdd(&acc[b0 + 0], __float2int_rn(h0.x * scale));
        atomicAdd(&acc[b0 + 1], __float2int_rn(h0.y * scale));
        atomicAdd(&acc[b0 + 2], __float2int_rn(h0.z * scale));
        atomicAdd(&acc[b1 + 0], __float2int_rn(h1.x * scale));
        atomicAdd(&acc[b1 + 1], __float2int_rn(h1.y * scale));
        atomicAdd(&acc[b1 + 2], __float2int_rn(h1.z * scale));
        atomicAdd(&acc[b2 + 0], __float2int_rn(h2.x * scale));
        atomicAdd(&acc[b2 + 1], __float2int_rn(h2.y * scale));
        atomicAdd(&acc[b2 + 2], __float2int_rn(h2.z * scale));
        atomicAdd(&acc[b3 + 0], __float2int_rn(h3.x * scale));
        atomicAdd(&acc[b3 + 1], __float2int_rn(h3.y * scale));
        atomicAdd(&acc[b3 + 2], __float2int_rn(h3.z * scale));
    }
    if (vend + t < en) {
        u32 v = bkt[vend + t];
        float4 h = tab[v & 0x1FFFFu];
        int bin = (int)(v >> 17) * 3;
        atomicAdd(&acc[bin + 0], __float2int_rn(h.x * scale));
        atomicAdd(&acc[bin + 1], __float2int_rn(h.y * scale));
        atomicAdd(&acc[bin + 2], __float2int_rn(h.z * scale));
    }
    __syncthreads();
    float* p = pacc + (size_t)blk * 6144;
#pragma unroll
    for (int k = 0; k < 8; ++k) {
        int bin = t + k * 256;
        p[bin]        = (float)acc[bin * 3 + 0] * inv_scale;   // planar c0
        p[bin + 2048] = (float)acc[bin * 3 + 1] * inv_scale;   // planar c1
        p[bin + 4096] = (float)acc[bin * 3 + 2] * inv_scale;   // planar c2
    }
}

// ====== fin1: combine 16 partials + self, @W1->leaky->@W2, *dinv ===========
__global__ void k_fin1B(const float* __restrict__ pacc, const float* __restrict__ dinv,
                        const float4* __restrict__ hd0,
                        const float* __restrict__ W1, const float* __restrict__ b1,
                        const float* __restrict__ W2,
                        float4* __restrict__ hd2, int nN) {
    int d = blockIdx.x * blockDim.x + threadIdx.x;
    if (d >= nN) return;
    int b = d >> 11, q = d & 2047;
    const float* pb = pacc + (size_t)b * ASPL2 * 6144;
    float s0 = 0.f, s1 = 0.f, s2 = 0.f;
#pragma unroll
    for (int s = 0; s < ASPL2; ++s) {
        const float* p = pb + s * 6144;
        s0 += p[q]; s1 += p[q + 2048]; s2 += p[q + 4096];
    }
    float di = dinv[d];
    float4 self = hd0[d];
    float a0 = di * (s0 + self.x);
    float a1 = di * (s1 + self.y);
    float a2 = di * (s2 + self.z);
    float o0 = 0.f, o1 = 0.f, o2 = 0.f;
#pragma unroll
    for (int k = 0; k < 16; ++k) {
        float p = leaky(a0 * W1[k] + a1 * W1[16 + k] + a2 * W1[32 + k] + b1[k]);
        o0 += p * W2[k * 3 + 0];
        o1 += p * W2[k * 3 + 1];
        o2 += p * W2[k * 3 + 2];
    }
    hd2[d] = make_float4(o0 * di, o1 * di, o2 * di, 0.f);
}

// ====== fin2 ===============================================================
__global__ void k_fin2B(const float* __restrict__ pacc, const float* __restrict__ dinv,
                        const float4* __restrict__ hd2, const float* __restrict__ b2,
                        float4* __restrict__ h2, int nN) {
    int d = blockIdx.x * blockDim.x + threadIdx.x;
    if (d >= nN) return;
    int b = d >> 11, q = d & 2047;
    const float* pb = pacc + (size_t)b * ASPL2 * 6144;
    float s0 = 0.f, s1 = 0.f, s2 = 0.f;
#pragma unroll
    for (int s = 0; s < ASPL2; ++s) {
        const float* p = pb + s * 6144;
        s0 += p[q]; s1 += p[q + 2048]; s2 += p[q + 4096];
    }
    float di = dinv[d];
    float4 self = hd2[d];
    h2[d] = make_float4(leaky(di * (s0 + self.x) + b2[0]),
                        leaky(di * (s1 + self.y) + b2[1]),
                        leaky(di * (s2 + self.z) + b2[2]), 0.f);
}

// ================= per-match MLP: 4 matches per thread =====================
__global__ __launch_bounds__(256) void k_mlp4v(
        const int* __restrict__ home, const int* __restrict__ away,
        const float4* __restrict__ h2,
        const float* __restrict__ lw1, const float* __restrict__ lb1,
        const float* __restrict__ lw2, const float* __restrict__ lb2,
        const float* __restrict__ lw3, const float* __restrict__ lb3,
        float* __restrict__ out, int nM) {
    __shared__ float s[235];
    int t = threadIdx.x;
    if (t < 96)       s[t] = lw1[t];
    else if (t < 112) s[t] = lb1[t - 96];
    else if (t < 208) s[t] = lw2[t - 112];
    else if (t < 214) s[t] = lb2[t - 208];
    else if (t < 232) s[t] = lw3[t - 214];
    else if (t < 235) s[t] = lb3[t - 232];
    __syncthreads();
    const float* sw1 = s;        const float* sb1 = s + 96;
    const float* sw2 = s + 112;  const float* sb2 = s + 208;
    const float* sw3 = s + 214;  const float* sb3 = s + 232;
    int i = blockIdx.x * blockDim.x + threadIdx.x;
    int m0 = i * 4;
    if (m0 >= nM) return;
    float res[12];
    int nq = min(4, nM - m0);
    int hidx[4], aidx[4];
    if (nq == 4) {
        int4 hv = *(const int4*)&home[m0];
        int4 av = *(const int4*)&away[m0];
        hidx[0] = hv.x; hidx[1] = hv.y; hidx[2] = hv.z; hidx[3] = hv.w;
        aidx[0] = av.x; aidx[1] = av.y; aidx[2] = av.z; aidx[3] = av.w;
    } else {
        for (int j = 0; j < nq; ++j) { hidx[j] = home[m0 + j]; aidx[j] = away[m0 + j]; }
    }
    for (int j = 0; j < nq; ++j) {
        float4 zh = h2[hidx[j]];
        float4 za = h2[aidx[j]];
        float z[6] = {zh.x, zh.y, zh.z, za.x, za.y, za.z};
        float t1[16];
#pragma unroll
        for (int k = 0; k < 16; ++k) {
            float p = sb1[k];
#pragma unroll
            for (int q = 0; q < 6; ++q) p += z[q] * sw1[q * 16 + k];
            t1[k] = leaky(p);
        }
        float t2[6];
#pragma unroll
        for (int k = 0; k < 6; ++k) {
            float p = sb2[k];
#pragma unroll
            for (int q = 0; q < 16; ++q) p += t1[q] * sw2[q * 6 + k];
            t2[k] = leaky(p);
        }
#pragma unroll
        for (int k = 0; k < 3; ++k) {
            float p = sb3[k];
#pragma unroll
            for (int q = 0; q < 6; ++q) p += t2[q] * sw3[q * 3 + k];
            res[j * 3 + k] = leaky(p);
        }
    }
    if (nq == 4) {
        float4* o4 = (float4*)&out[m0 * 3];
        o4[0] = make_float4(res[0], res[1], res[2], res[3]);
        o4[1] = make_float4(res[4], res[5], res[6], res[7]);
        o4[2] = make_float4(res[8], res[9], res[10], res[11]);
    } else {
        for (int j = 0; j < nq * 3; ++j) out[m0 * 3 + j] = res[j];
    }
}

// ================= tiny fallback (float-atomic push) =======================
__global__ void f_deg(const int* __restrict__ dst, float* __restrict__ deg, int nE) {
    int e = blockIdx.x * blockDim.x + threadIdx.x;
    if (e < nE) atomicAdd(&deg[dst[e]], 1.0f);
}
__global__ void f_hd0(const int* __restrict__ x, const float* __restrict__ emb,
                      float* __restrict__ dinv, float4* __restrict__ hd0, int nN) {
    int i = blockIdx.x * blockDim.x + threadIdx.x;
    if (i >= nN) return;
    float di = rsqrtf(dinv[i] + 1.0f);
    dinv[i] = di;
    int xi = x[i] * 3;
    hd0[i] = make_float4(emb[xi] * di, emb[xi + 1] * di, emb[xi + 2] * di, 0.f);
}
__global__ void f_scatter(const int* __restrict__ src, const int* __restrict__ dst,
                          const float4* __restrict__ tab, float* __restrict__ agg, int nE) {
    int e = blockIdx.x * blockDim.x + threadIdx.x;
    if (e >= nE) return;
    int s = src[e], d = dst[e];
    float4 v = tab[s];
    atomicAdd(&agg[d * 3 + 0], v.x);
    atomicAdd(&agg[d * 3 + 1], v.y);
    atomicAdd(&agg[d * 3 + 2], v.z);
}
__global__ void f_fin1(const float* __restrict__ agg, const float* __restrict__ dinv,
                       const float4* __restrict__ hd0,
                       const float* __restrict__ W1, const float* __restrict__ b1,
                       const float* __restrict__ W2, float4* __restrict__ hd2, int nN) {
    int d = blockIdx.x * blockDim.x + threadIdx.x;
    if (d >= nN) return;
    float di = dinv[d];
    float4 self = hd0[d];
    float a0 = di * (agg[d * 3 + 0] + self.x);
    float a1 = di * (agg[d * 3 + 1] + self.y);
    float a2 = di * (agg[d * 3 + 2] + self.z);
    float o0 = 0.f, o1 = 0.f, o2 = 0.f;
#pragma unroll
    for (int k = 0; k < 16; ++k) {
        float p = leaky(a0 * W1[k] + a1 * W1[16 + k] + a2 * W1[32 + k] + b1[k]);
        o0 += p * W2[k * 3 + 0];
        o1 += p * W2[k * 3 + 1];
        o2 += p * W2[k * 3 + 2];
    }
    hd2[d] = make_float4(o0 * di, o1 * di, o2 * di, 0.f);
}
__global__ void f_fin2(const float* __restrict__ agg, const float* __restrict__ dinv,
                       const float4* __restrict__ hd2, const float* __restrict__ b2,
                       float4* __restrict__ h2, int nN) {
    int d = blockIdx.x * blockDim.x + threadIdx.x;
    if (d >= nN) return;
    float di = dinv[d];
    float4 self = hd2[d];
    h2[d] = make_float4(leaky(di * (agg[d * 3 + 0] + self.x) + b2[0]),
                        leaky(di * (agg[d * 3 + 1] + self.y) + b2[1]),
                        leaky(di * (agg[d * 3 + 2] + self.z) + b2[2]), 0.f);
}

// ================= launch =================
extern "C" void kernel_launch(void* const* d_in, const int* in_sizes, int n_in,
                              void* d_out, int out_size, void* d_ws, size_t ws_size,
                              hipStream_t stream) {
    const int*   x    = (const int*)d_in[0];
    const int*   ei   = (const int*)d_in[1];
    const int*   home = (const int*)d_in[2];
    const int*   away = (const int*)d_in[3];
    const float* emb  = (const float*)d_in[4];
    const float* W1   = (const float*)d_in[5];
    const float* b1   = (const float*)d_in[6];
    const float* W2   = (const float*)d_in[7];
    const float* b2   = (const float*)d_in[8];
    const float* lw1  = (const float*)d_in[9];
    const float* lb1  = (const float*)d_in[10];
    const float* lw2  = (const float*)d_in[11];
    const float* lb2  = (const float*)d_in[12];
    const float* lw3  = (const float*)d_in[13];
    const float* lb3  = (const float*)d_in[14];
    float* out = (float*)d_out;

    const int nN = in_sizes[0];       // 100000
    const int nE = in_sizes[1] / 2;   // 5M
    const int nM = in_sizes[2];       // 1M
    const int* src = ei;
    const int* dst = ei + nE;
    const int B = 256;

    const int nb1 = (nE + P1C - 1) / P1C;
    const int nB2 = (nN + 2047) / 2048;                     // active buckets (49)
    const size_t bktN = (size_t)nB2 << CAP2_LOG;            // u32
    const size_t paccN = (size_t)nB2 * ASPL2 * 6144;        // floats

    size_t need = (size_t)3 * nN * 16 + bktN * 4 + paccN * 4 +
                  (size_t)nN * 4 + NB2 * 4;

    // capacity: per-bucket mean = nE*2048/nN, +10 sigma must fit 1<<CAP2_LOG
    double mean_b = (double)nE * 2048.0 / (double)nN;
    double sig_b = sqrt(mean_b);
    bool cap_ok = (mean_b + 10.0 * sig_b) < (double)(1 << CAP2_LOG);

    if (nN <= NB2 * 2048 && ws_size >= need && cap_ok) {
        char* w = (char*)d_ws;
        float4* hd0 = (float4*)w;                 w += (size_t)nN * 16;
        float4* hd2 = (float4*)w;                 w += (size_t)nN * 16;
        float4* h2  = (float4*)w;                 w += (size_t)nN * 16;
        u32* bkt  = (u32*)w;                      w += bktN * 4;
        float* pacc = (float*)w;                  w += paccN * 4;
        float* dinv = (float*)w;                  w += (size_t)nN * 4;
        int* cur  = (int*)w;

        hipMemsetAsync(cur, 0, NB2 * sizeof(int), stream);
        k_p1scatterB<<<nb1, 256, 0, stream>>>(src, dst, cur, bkt, nE);
        k_cntB<<<nB2, 256, 0, stream>>>(bkt, cur, x, emb, dinv, hd0, nN);
        k_aggB<<<nB2 * ASPL2, 256, 0, stream>>>(bkt, cur, hd0, pacc,
                                                S1F, 1.0f / S1F);
        k_fin1B<<<(nN + B - 1) / B, B, 0, stream>>>(pacc, dinv, hd0, W1, b1, W2,
                                                    hd2, nN);
        k_aggB<<<nB2 * ASPL2, 256, 0, stream>>>(bkt, cur, hd2, pacc,
                                                S2F, 1.0f / S2F);
        k_fin2B<<<(nN + B - 1) / B, B, 0, stream>>>(pacc, dinv, hd2, b2, h2, nN);
        int nQuads = (nM + 3) / 4;
        k_mlp4v<<<(nQuads + B - 1) / B, B, 0, stream>>>(home, away, h2,
                                                        lw1, lb1, lw2, lb2,
                                                        lw3, lb3, out, nM);
    } else {
        // compact float-atomic fallback (correct, slower)
        char* w = (char*)d_ws;
        float4* hd0 = (float4*)w;                 w += (size_t)nN * 16;
        float4* hd2 = (float4*)w;                 w += (size_t)nN * 16;
        float4* h2  = (float4*)w;                 w += (size_t)nN * 16;
        float* agg  = (float*)w;                  w += (size_t)3 * nN * 4;
        float* dinv = (float*)w;

        hipMemsetAsync(dinv, 0, (size_t)nN * sizeof(float), stream);
        hipMemsetAsync(agg, 0, (size_t)3 * nN * sizeof(float), stream);
        f_deg<<<(nE + B - 1) / B, B, 0, stream>>>(dst, dinv, nE);
        f_hd0<<<(nN + B - 1) / B, B, 0, stream>>>(x, emb, dinv, hd0, nN);
        f_scatter<<<(nE + B - 1) / B, B, 0, stream>>>(src, dst, hd0, agg, nE);
        f_fin1<<<(nN + B - 1) / B, B, 0, stream>>>(agg, dinv, hd0, W1, b1, W2, hd2, nN);
        hipMemsetAsync(agg, 0, (size_t)3 * nN * sizeof(float), stream);
        f_scatter<<<(nE + B - 1) / B, B, 0, stream>>>(src, dst, hd2, agg, nE);
        f_fin2<<<(nN + B - 1) / B, B, 0, stream>>>(agg, dinv, hd2, b2, h2, nN);
        int nQuads = (nM + 3) / 4;
        k_mlp4v<<<(nQuads + B - 1) / B, B, 0, stream>>>(home, away, h2,
                                                        lw1, lb1, lw2, lb2,
                                                        lw3, lb3, out, nM);
    }
}

// Round 14
// 130.621 us; speedup vs baseline: 1.3507x; 1.3507x over previous
//
#include <hip/hip_runtime.h>

typedef unsigned int u32;
typedef unsigned short u16;

static __device__ __forceinline__ float leaky(float v) {
    return v >= 0.0f ? v : 0.01f * v;
}

#define P1_CHUNK 8192
#define P1T 512            // scatter block threads (8 waves)
#define NBK 512            // buckets = dst>>8  (requires nN <= 131072)
#define CAPB 16384         // per-bucket capacity; mean load nE*256/nN = 12800
#define ASPLIT 8
#define S1F 8388608.0f     // 2^23 fixed-point scale, layer 1
#define S2F 2097152.0f     // 2^21 fixed-point scale, layer 2

// ====== scatter: block reservation, 8-wave shuffle scan, 512 threads =======
__global__ __launch_bounds__(512) void k_p1scatterA(
        const int* __restrict__ src, const int* __restrict__ dst,
        int* __restrict__ cur, u32* __restrict__ bkt, int nE) {
    __shared__ int sc[NBK];
    __shared__ int loff[NBK];
    __shared__ int gb[NBK];
    __shared__ int lcur[NBK];
    __shared__ int wsum[8];
    __shared__ u32 pay[P1_CHUNK];
    __shared__ u16 bb[P1_CHUNK];
    int t = threadIdx.x;
    sc[t] = 0;                              // P1T == NBK == 512
    __syncthreads();
    int base = blockIdx.x * P1_CHUNK;
    int lim = min(P1_CHUNK, nE - base);
    if (lim == P1_CHUNK) {
        const int4* p = (const int4*)(dst + base);
        for (int i = t; i < P1_CHUNK / 4; i += P1T) {
            int4 v = p[i];
            atomicAdd(&sc[v.x >> 8], 1);
            atomicAdd(&sc[v.y >> 8], 1);
            atomicAdd(&sc[v.z >> 8], 1);
            atomicAdd(&sc[v.w >> 8], 1);
        }
    } else {
        for (int i = t; i < lim; i += P1T)
            atomicAdd(&sc[dst[base + i] >> 8], 1);
    }
    __syncthreads();
    // 8-wave shuffle scan over 512 counts (2 barriers total)
    int c = sc[t];
    int lane = t & 63;
    int incl = c;
#pragma unroll
    for (int o = 1; o < 64; o <<= 1) {
        int xv = __shfl_up(incl, o);
        if (lane >= o) incl += xv;
    }
    if (lane == 63) wsum[t >> 6] = incl;
    __syncthreads();
    if (t == 0) {
        int run = 0;
#pragma unroll
        for (int k = 0; k < 8; ++k) { int v = wsum[k]; wsum[k] = run; run += v; }
    }
    __syncthreads();
    {
        int excl = incl - c + wsum[t >> 6];
        loff[t] = excl;
        lcur[t] = excl;
        gb[t] = (t << 14) + ((c > 0) ? atomicAdd(&cur[t], c) : 0);
    }
    __syncthreads();
    int n4 = lim >> 2;
    const int4* d4p = (const int4*)(dst + base);
    const int4* s4p = (const int4*)(src + base);
    for (int i = t; i < n4; i += P1T) {
        int4 d4 = d4p[i];
        int4 s4 = s4p[i];
        int b, r;
        b = d4.x >> 8; r = atomicAdd(&lcur[b], 1);
        pay[r] = (u32)(((d4.x & 255) << 17) | s4.x); bb[r] = (u16)b;
        b = d4.y >> 8; r = atomicAdd(&lcur[b], 1);
        pay[r] = (u32)(((d4.y & 255) << 17) | s4.y); bb[r] = (u16)b;
        b = d4.z >> 8; r = atomicAdd(&lcur[b], 1);
        pay[r] = (u32)(((d4.z & 255) << 17) | s4.z); bb[r] = (u16)b;
        b = d4.w >> 8; r = atomicAdd(&lcur[b], 1);
        pay[r] = (u32)(((d4.w & 255) << 17) | s4.w); bb[r] = (u16)b;
    }
    for (int i = (n4 << 2) + t; i < lim; i += P1T) {
        int d = dst[base + i], s = src[base + i];
        int b = d >> 8;
        int r = atomicAdd(&lcur[b], 1);
        pay[r] = (u32)(((d & 255) << 17) | s);
        bb[r] = (u16)b;
    }
    __syncthreads();
    for (int i = t; i < lim; i += P1T) {
        int b = bb[i];
        bkt[gb[b] + (i - loff[b])] = pay[i];
    }
}

// ====== cnt: per-bucket degree histogram -> dinv + hd0 (1024 threads) ======
__global__ __launch_bounds__(1024) void k_cnt1F(
        const u32* __restrict__ bkt, const int* __restrict__ cur,
        const int* __restrict__ x, const float* __restrict__ emb,
        float* __restrict__ dinv, float4* __restrict__ hd0, int nN) {
    __shared__ int h[256];
    int t = threadIdx.x, b = blockIdx.x;
    if (t < 256) h[t] = 0;
    __syncthreads();
    int base = b << 14;
    int end = base + cur[b];
    int vend = base + ((end - base) & ~3);   // base 16B-aligned
    for (int i = base + t * 4; i < vend; i += 1024 * 4) {
        uint4 v = *(const uint4*)&bkt[i];
        atomicAdd(&h[v.x >> 17], 1);
        atomicAdd(&h[v.y >> 17], 1);
        atomicAdd(&h[v.z >> 17], 1);
        atomicAdd(&h[v.w >> 17], 1);
    }
    if (vend + t < end) atomicAdd(&h[bkt[vend + t] >> 17], 1);
    __syncthreads();
    if (t < 256) {
        int d = b * 256 + t;
        if (d < nN) {
            float di = rsqrtf((float)h[t] + 1.0f);
            dinv[d] = di;
            int xi = x[d] * 3;
            hd0[d] = make_float4(emb[xi] * di, emb[xi + 1] * di,
                                 emb[xi + 2] * di, 0.f);
        }
    }
}

// ====== aggI: fixed-point LDS accumulation (int atomics only), ASPLIT=8 ====
__global__ __launch_bounds__(256) void k_aggIF(
        const u32* __restrict__ bkt, const int* __restrict__ cur,
        const float4* __restrict__ tab, float* __restrict__ pacc,
        float scale, float inv_scale) {
    __shared__ int acc[768];
    int t = threadIdx.x;
    int blk = blockIdx.x, b = blk >> 3, s = blk & 7;
    int base = b << 14;
    int sz = cur[b];
    int chunk = (sz + ASPLIT - 1) / ASPLIT;
    int st = min(base + s * chunk, base + sz);
    int en = min(st + chunk, base + sz);
    acc[t] = 0; acc[t + 256] = 0; acc[t + 512] = 0;
    __syncthreads();
    int a0 = min((st + 3) & ~3, en);
    if (st + t < a0) {
        u32 v = bkt[st + t];
        float4 h = tab[v & 0x1FFFFu];
        int bin = (int)(v >> 17) * 3;
        atomicAdd(&acc[bin + 0], __float2int_rn(h.x * scale));
        atomicAdd(&acc[bin + 1], __float2int_rn(h.y * scale));
        atomicAdd(&acc[bin + 2], __float2int_rn(h.z * scale));
    }
    int vend = a0 + ((en - a0) & ~3);
    for (int i = a0 + t * 4; i < vend; i += 256 * 4) {
        uint4 v = *(const uint4*)&bkt[i];
        float4 h0 = tab[v.x & 0x1FFFFu];
        float4 h1 = tab[v.y & 0x1FFFFu];
        float4 h2 = tab[v.z & 0x1FFFFu];
        float4 h3 = tab[v.w & 0x1FFFFu];
        int b0 = (int)(v.x >> 17) * 3, b1 = (int)(v.y >> 17) * 3;
        int b2 = (int)(v.z >> 17) * 3, b3 = (int)(v.w >> 17) * 3;
        atomicAdd(&acc[b0 + 0], __float2int_rn(h0.x * scale));
        atomicAdd(&acc[b0 + 1], __float2int_rn(h0.y * scale));
        atomicAdd(&acc[b0 + 2], __float2int_rn(h0.z * scale));
        atomicAdd(&acc[b1 + 0], __float2int_rn(h1.x * scale));
        atomicAdd(&acc[b1 + 1], __float2int_rn(h1.y * scale));
        atomicAdd(&acc[b1 + 2], __float2int_rn(h1.z * scale));
        atomicAdd(&acc[b2 + 0], __float2int_rn(h2.x * scale));
        atomicAdd(&acc[b2 + 1], __float2int_rn(h2.y * scale));
        atomicAdd(&acc[b2 + 2], __float2int_rn(h2.z * scale));
        atomicAdd(&acc[b3 + 0], __float2int_rn(h3.x * scale));
        atomicAdd(&acc[b3 + 1], __float2int_rn(h3.y * scale));
        atomicAdd(&acc[b3 + 2], __float2int_rn(h3.z * scale));
    }
    if (vend + t < en) {
        u32 v = bkt[vend + t];
        float4 h = tab[v & 0x1FFFFu];
        int bin = (int)(v >> 17) * 3;
        atomicAdd(&acc[bin + 0], __float2int_rn(h.x * scale));
        atomicAdd(&acc[bin + 1], __float2int_rn(h.y * scale));
        atomicAdd(&acc[bin + 2], __float2int_rn(h.z * scale));
    }
    __syncthreads();
    float* p = pacc + (size_t)blk * 768;
    p[t]       = (float)acc[t * 3 + 0] * inv_scale;
    p[t + 256] = (float)acc[t * 3 + 1] * inv_scale;
    p[t + 512] = (float)acc[t * 3 + 2] * inv_scale;
}

// ====== fin1: combine partials + self, chain @W1->leaky->@W2, *dinv ========
__global__ void k_fin1(const float* __restrict__ pacc, const float* __restrict__ dinv,
                       const float4* __restrict__ hd0,
                       const float* __restrict__ W1, const float* __restrict__ b1,
                       const float* __restrict__ W2,
                       float4* __restrict__ hd2, int nN) {
    int d = blockIdx.x * blockDim.x + threadIdx.x;
    if (d >= nN) return;
    int b = d >> 8, q = d & 255;
    float s0 = 0.f, s1 = 0.f, s2 = 0.f;
#pragma unroll
    for (int s = 0; s < ASPLIT; ++s) {
        const float* p = pacc + (size_t)(b * ASPLIT + s) * 768;
        s0 += p[q]; s1 += p[q + 256]; s2 += p[q + 512];
    }
    float di = dinv[d];
    float4 self = hd0[d];
    float a0 = di * (s0 + self.x);
    float a1 = di * (s1 + self.y);
    float a2 = di * (s2 + self.z);
    float o0 = 0.f, o1 = 0.f, o2 = 0.f;
#pragma unroll
    for (int k = 0; k < 16; ++k) {
        float p = leaky(a0 * W1[k] + a1 * W1[16 + k] + a2 * W1[32 + k] + b1[k]);
        o0 += p * W2[k * 3 + 0];
        o1 += p * W2[k * 3 + 1];
        o2 += p * W2[k * 3 + 2];
    }
    hd2[d] = make_float4(o0 * di, o1 * di, o2 * di, 0.f);
}

// ====== fin2 ===============================================================
__global__ void k_fin2(const float* __restrict__ pacc, const float* __restrict__ dinv,
                       const float4* __restrict__ hd2, const float* __restrict__ b2,
                       float4* __restrict__ h2, int nN) {
    int d = blockIdx.x * blockDim.x + threadIdx.x;
    if (d >= nN) return;
    int b = d >> 8, q = d & 255;
    float s0 = 0.f, s1 = 0.f, s2 = 0.f;
#pragma unroll
    for (int s = 0; s < ASPLIT; ++s) {
        const float* p = pacc + (size_t)(b * ASPLIT + s) * 768;
        s0 += p[q]; s1 += p[q + 256]; s2 += p[q + 512];
    }
    float di = dinv[d];
    float4 self = hd2[d];
    h2[d] = make_float4(leaky(di * (s0 + self.x) + b2[0]),
                        leaky(di * (s1 + self.y) + b2[1]),
                        leaky(di * (s2 + self.z) + b2[2]), 0.f);
}

// ================= per-match MLP: 4 matches per thread =====================
__global__ __launch_bounds__(256) void k_mlp4v(
        const int* __restrict__ home, const int* __restrict__ away,
        const float4* __restrict__ h2,
        const float* __restrict__ lw1, const float* __restrict__ lb1,
        const float* __restrict__ lw2, const float* __restrict__ lb2,
        const float* __restrict__ lw3, const float* __restrict__ lb3,
        float* __restrict__ out, int nM) {
    __shared__ float s[235];
    int t = threadIdx.x;
    if (t < 96)       s[t] = lw1[t];
    else if (t < 112) s[t] = lb1[t - 96];
    else if (t < 208) s[t] = lw2[t - 112];
    else if (t < 214) s[t] = lb2[t - 208];
    else if (t < 232) s[t] = lw3[t - 214];
    else if (t < 235) s[t] = lb3[t - 232];
    __syncthreads();
    const float* sw1 = s;        const float* sb1 = s + 96;
    const float* sw2 = s + 112;  const float* sb2 = s + 208;
    const float* sw3 = s + 214;  const float* sb3 = s + 232;
    int i = blockIdx.x * blockDim.x + threadIdx.x;
    int m0 = i * 4;
    if (m0 >= nM) return;
    float res[12];
    int nq = min(4, nM - m0);
    int hidx[4], aidx[4];
    if (nq == 4) {
        int4 hv = *(const int4*)&home[m0];
        int4 av = *(const int4*)&away[m0];
        hidx[0] = hv.x; hidx[1] = hv.y; hidx[2] = hv.z; hidx[3] = hv.w;
        aidx[0] = av.x; aidx[1] = av.y; aidx[2] = av.z; aidx[3] = av.w;
    } else {
        for (int j = 0; j < nq; ++j) { hidx[j] = home[m0 + j]; aidx[j] = away[m0 + j]; }
    }
    for (int j = 0; j < nq; ++j) {
        float4 zh = h2[hidx[j]];
        float4 za = h2[aidx[j]];
        float z[6] = {zh.x, zh.y, zh.z, za.x, za.y, za.z};
        float t1[16];
#pragma unroll
        for (int k = 0; k < 16; ++k) {
            float p = sb1[k];
#pragma unroll
            for (int q = 0; q < 6; ++q) p += z[q] * sw1[q * 16 + k];
            t1[k] = leaky(p);
        }
        float t2[6];
#pragma unroll
        for (int k = 0; k < 6; ++k) {
            float p = sb2[k];
#pragma unroll
            for (int q = 0; q < 16; ++q) p += t1[q] * sw2[q * 6 + k];
            t2[k] = leaky(p);
        }
#pragma unroll
        for (int k = 0; k < 3; ++k) {
            float p = sb3[k];
#pragma unroll
            for (int q = 0; q < 6; ++q) p += t2[q] * sw3[q * 3 + k];
            res[j * 3 + k] = leaky(p);
        }
    }
    if (nq == 4) {
        float4* o4 = (float4*)&out[m0 * 3];
        o4[0] = make_float4(res[0], res[1], res[2], res[3]);
        o4[1] = make_float4(res[4], res[5], res[6], res[7]);
        o4[2] = make_float4(res[8], res[9], res[10], res[11]);
    } else {
        for (int j = 0; j < nq * 3; ++j) out[m0 * 3 + j] = res[j];
    }
}

// ================= tiny fallback (float-atomic push) =======================
__global__ void f_deg(const int* __restrict__ dst, float* __restrict__ deg, int nE) {
    int e = blockIdx.x * blockDim.x + threadIdx.x;
    if (e < nE) atomicAdd(&deg[dst[e]], 1.0f);
}
__global__ void f_hd0(const int* __restrict__ x, const float* __restrict__ emb,
                      float* __restrict__ dinv, float4* __restrict__ hd0, int nN) {
    int i = blockIdx.x * blockDim.x + threadIdx.x;
    if (i >= nN) return;
    float di = rsqrtf(dinv[i] + 1.0f);
    dinv[i] = di;
    int xi = x[i] * 3;
    hd0[i] = make_float4(emb[xi] * di, emb[xi + 1] * di, emb[xi + 2] * di, 0.f);
}
__global__ void f_scatter(const int* __restrict__ src, const int* __restrict__ dst,
                          const float4* __restrict__ tab, float* __restrict__ agg, int nE) {
    int e = blockIdx.x * blockDim.x + threadIdx.x;
    if (e >= nE) return;
    int s = src[e], d = dst[e];
    float4 v = tab[s];
    atomicAdd(&agg[d * 3 + 0], v.x);
    atomicAdd(&agg[d * 3 + 1], v.y);
    atomicAdd(&agg[d * 3 + 2], v.z);
}
__global__ void f_fin1(const float* __restrict__ agg, const float* __restrict__ dinv,
                       const float4* __restrict__ hd0,
                       const float* __restrict__ W1, const float* __restrict__ b1,
                       const float* __restrict__ W2, float4* __restrict__ hd2, int nN) {
    int d = blockIdx.x * blockDim.x + threadIdx.x;
    if (d >= nN) return;
    float di = dinv[d];
    float4 self = hd0[d];
    float a0 = di * (agg[d * 3 + 0] + self.x);
    float a1 = di * (agg[d * 3 + 1] + self.y);
    float a2 = di * (agg[d * 3 + 2] + self.z);
    float o0 = 0.f, o1 = 0.f, o2 = 0.f;
#pragma unroll
    for (int k = 0; k < 16; ++k) {
        float p = leaky(a0 * W1[k] + a1 * W1[16 + k] + a2 * W1[32 + k] + b1[k]);
        o0 += p * W2[k * 3 + 0];
        o1 += p * W2[k * 3 + 1];
        o2 += p * W2[k * 3 + 2];
    }
    hd2[d] = make_float4(o0 * di, o1 * di, o2 * di, 0.f);
}
__global__ void f_fin2(const float* __restrict__ agg, const float* __restrict__ dinv,
                       const float4* __restrict__ hd2, const float* __restrict__ b2,
                       float4* __restrict__ h2, int nN) {
    int d = blockIdx.x * blockDim.x + threadIdx.x;
    if (d >= nN) return;
    float di = dinv[d];
    float4 self = hd2[d];
    h2[d] = make_float4(leaky(di * (agg[d * 3 + 0] + self.x) + b2[0]),
                        leaky(di * (agg[d * 3 + 1] + self.y) + b2[1]),
                        leaky(di * (agg[d * 3 + 2] + self.z) + b2[2]), 0.f);
}

// ================= launch =================
extern "C" void kernel_launch(void* const* d_in, const int* in_sizes, int n_in,
                              void* d_out, int out_size, void* d_ws, size_t ws_size,
                              hipStream_t stream) {
    const int*   x    = (const int*)d_in[0];
    const int*   ei   = (const int*)d_in[1];
    const int*   home = (const int*)d_in[2];
    const int*   away = (const int*)d_in[3];
    const float* emb  = (const float*)d_in[4];
    const float* W1   = (const float*)d_in[5];
    const float* b1   = (const float*)d_in[6];
    const float* W2   = (const float*)d_in[7];
    const float* b2   = (const float*)d_in[8];
    const float* lw1  = (const float*)d_in[9];
    const float* lb1  = (const float*)d_in[10];
    const float* lw2  = (const float*)d_in[11];
    const float* lb2  = (const float*)d_in[12];
    const float* lw3  = (const float*)d_in[13];
    const float* lb3  = (const float*)d_in[14];
    float* out = (float*)d_out;

    const int nN = in_sizes[0];       // 100000
    const int nE = in_sizes[1] / 2;   // 5M
    const int nM = in_sizes[2];       // 1M
    const int* src = ei;
    const int* dst = ei + nE;
    const int B = 256;

    const int nb1 = (nE + P1_CHUNK - 1) / P1_CHUNK;
    const size_t paccN = (size_t)NBK * ASPLIT * 768;        // floats
    const size_t bktN = (size_t)NBK * CAPB;                 // u32 (33.5 MB)

    size_t need = (size_t)3 * nN * 16 + bktN * 4 + paccN * 4 +
                  (size_t)nN * 4 + NBK * 4;

    // capacity: per-bucket mean = nE*256/nN (uniform dst over nN nodes)
    double mean_b = (double)nE * 256.0 / (double)nN;
    double sig_b = sqrt(mean_b);
    bool cap_ok = (mean_b + 10.0 * sig_b) < (double)CAPB;

    if (nN <= NBK * 256 && ws_size >= need && cap_ok) {
        char* w = (char*)d_ws;
        float4* hd0 = (float4*)w;                 w += (size_t)nN * 16;
        float4* hd2 = (float4*)w;                 w += (size_t)nN * 16;
        float4* h2  = (float4*)w;                 w += (size_t)nN * 16;
        u32* bkt  = (u32*)w;                      w += bktN * 4;
        float* pacc = (float*)w;                  w += paccN * 4;
        float* dinv = (float*)w;                  w += (size_t)nN * 4;
        int* cur  = (int*)w;

        hipMemsetAsync(cur, 0, NBK * sizeof(int), stream);
        k_p1scatterA<<<nb1, P1T, 0, stream>>>(src, dst, cur, bkt, nE);
        k_cnt1F<<<NBK, 1024, 0, stream>>>(bkt, cur, x, emb, dinv, hd0, nN);
        k_aggIF<<<NBK * ASPLIT, 256, 0, stream>>>(bkt, cur, hd0, pacc,
                                                  S1F, 1.0f / S1F);
        k_fin1<<<(nN + B - 1) / B, B, 0, stream>>>(pacc, dinv, hd0, W1, b1, W2,
                                                   hd2, nN);
        k_aggIF<<<NBK * ASPLIT, 256, 0, stream>>>(bkt, cur, hd2, pacc,
                                                  S2F, 1.0f / S2F);
        k_fin2<<<(nN + B - 1) / B, B, 0, stream>>>(pacc, dinv, hd2, b2, h2, nN);
        int nQuads = (nM + 3) / 4;
        k_mlp4v<<<(nQuads + B - 1) / B, B, 0, stream>>>(home, away, h2,
                                                        lw1, lb1, lw2, lb2,
                                                        lw3, lb3, out, nM);
    } else {
        // compact float-atomic fallback (correct, slower)
        char* w = (char*)d_ws;
        float4* hd0 = (float4*)w;                 w += (size_t)nN * 16;
        float4* hd2 = (float4*)w;                 w += (size_t)nN * 16;
        float4* h2  = (float4*)w;                 w += (size_t)nN * 16;
        float* agg  = (float*)w;                  w += (size_t)3 * nN * 4;
        float* dinv = (float*)w;

        hipMemsetAsync(dinv, 0, (size_t)nN * sizeof(float), stream);
        hipMemsetAsync(agg, 0, (size_t)3 * nN * sizeof(float), stream);
        f_deg<<<(nE + B - 1) / B, B, 0, stream>>>(dst, dinv, nE);
        f_hd0<<<(nN + B - 1) / B, B, 0, stream>>>(x, emb, dinv, hd0, nN);
        f_scatter<<<(nE + B - 1) / B, B, 0, stream>>>(src, dst, hd0, agg, nE);
        f_fin1<<<(nN + B - 1) / B, B, 0, stream>>>(agg, dinv, hd0, W1, b1, W2, hd2, nN);
        hipMemsetAsync(agg, 0, (size_t)3 * nN * sizeof(float), stream);
        f_scatter<<<(nE + B - 1) / B, B, 0, stream>>>(src, dst, hd2, agg, nE);
        f_fin2<<<(nN + B - 1) / B, B, 0, stream>>>(agg, dinv, hd2, b2, h2, nN);
        int nQuads = (nM + 3) / 4;
        k_mlp4v<<<(nQuads + B - 1) / B, B, 0, stream>>>(home, away, h2,
                                                        lw1, lb1, lw2, lb2,
                                                        lw3, lb3, out, nM);
    }
}

// Round 15
// 128.665 us; speedup vs baseline: 1.3712x; 1.0152x over previous
//
#include <hip/hip_runtime.h>

typedef unsigned int u32;
typedef unsigned char u8;

static __device__ __forceinline__ float leaky(float v) {
    return v >= 0.0f ? v : 0.01f * v;
}

#define P1_CHUNK 8192
#define P1T 1024           // scatter block threads (16 waves; 2 blocks/CU = 100%)
#define NBK 512            // buckets = dst>>8  (requires nN <= 131072)
#define CAPB 16384         // per-bucket capacity; mean load nE*256/nN = 12800
#define ASPLIT 8
#define S1F 8388608.0f     // 2^23 fixed-point scale, layer 1
#define S2F 2097152.0f     // 2^21 fixed-point scale, layer 2

// ====== scatter: block reservation, 8-wave shuffle scan, u8 bucket tag =====
__global__ __launch_bounds__(1024) void k_p1scatterA(
        const int* __restrict__ src, const int* __restrict__ dst,
        int* __restrict__ cur, u32* __restrict__ bkt, int nE) {
    __shared__ int sc[NBK];
    __shared__ int loff[NBK];
    __shared__ int gb[NBK];
    __shared__ int lcur[NBK];
    __shared__ int wsum[8];
    __shared__ u32 pay[P1_CHUNK];
    __shared__ u8 bb[P1_CHUNK];     // low 8 bits of bucket; bit8 = (i >= loff[256])
    int t = threadIdx.x;
    if (t < NBK) sc[t] = 0;
    __syncthreads();
    int base = blockIdx.x * P1_CHUNK;
    int lim = min(P1_CHUNK, nE - base);
    if (lim == P1_CHUNK) {
        const int4* p = (const int4*)(dst + base);
        for (int i = t; i < P1_CHUNK / 4; i += P1T) {
            int4 v = p[i];
            atomicAdd(&sc[v.x >> 8], 1);
            atomicAdd(&sc[v.y >> 8], 1);
            atomicAdd(&sc[v.z >> 8], 1);
            atomicAdd(&sc[v.w >> 8], 1);
        }
    } else {
        for (int i = t; i < lim; i += P1T)
            atomicAdd(&sc[dst[base + i] >> 8], 1);
    }
    __syncthreads();
    // 8-wave shuffle scan over 512 counts (threads < 512)
    if (t < NBK) {
        int c = sc[t];
        int lane = t & 63;
        int incl = c;
#pragma unroll
        for (int o = 1; o < 64; o <<= 1) {
            int xv = __shfl_up(incl, o);
            if (lane >= o) incl += xv;
        }
        if (lane == 63) wsum[t >> 6] = incl;
        sc[t] = incl;                       // stash inclusive per-wave scan
    }
    __syncthreads();
    if (t == 0) {
        int run = 0;
#pragma unroll
        for (int k = 0; k < 8; ++k) { int v = wsum[k]; wsum[k] = run; run += v; }
    }
    __syncthreads();
    if (t < NBK) {
        int c;
        {
            // recover count: incl - (prev incl) not stored; recompute from hist?
            // sc[t] currently holds per-wave inclusive; c was overwritten.
            // Use difference: excl = sc[t] - c + wsum -> need c. Recompute:
            int inclw = sc[t];
            int prev = (t & 63) ? sc[t - 1] : 0;   // within-wave exclusive
            c = inclw - prev;
            int excl = prev + wsum[t >> 6];
            loff[t] = excl;
            lcur[t] = excl;
            gb[t] = (t << 14) + ((c > 0) ? atomicAdd(&cur[t], c) : 0);
        }
    }
    __syncthreads();
    int loff256 = loff[256];
    int n4 = lim >> 2;
    const int4* d4p = (const int4*)(dst + base);
    const int4* s4p = (const int4*)(src + base);
    for (int i = t; i < n4; i += P1T) {
        int4 d4 = d4p[i];
        int4 s4 = s4p[i];
        int b, r;
        b = d4.x >> 8; r = atomicAdd(&lcur[b], 1);
        pay[r] = (u32)(((d4.x & 255) << 17) | s4.x); bb[r] = (u8)b;
        b = d4.y >> 8; r = atomicAdd(&lcur[b], 1);
        pay[r] = (u32)(((d4.y & 255) << 17) | s4.y); bb[r] = (u8)b;
        b = d4.z >> 8; r = atomicAdd(&lcur[b], 1);
        pay[r] = (u32)(((d4.z & 255) << 17) | s4.z); bb[r] = (u8)b;
        b = d4.w >> 8; r = atomicAdd(&lcur[b], 1);
        pay[r] = (u32)(((d4.w & 255) << 17) | s4.w); bb[r] = (u8)b;
    }
    for (int i = (n4 << 2) + t; i < lim; i += P1T) {
        int d = dst[base + i], s = src[base + i];
        int b = d >> 8;
        int r = atomicAdd(&lcur[b], 1);
        pay[r] = (u32)(((d & 255) << 17) | s);
        bb[r] = (u8)b;
    }
    __syncthreads();
    for (int i = t; i < lim; i += P1T) {
        int b = (int)bb[i] | ((i >= loff256) ? 256 : 0);
        bkt[gb[b] + (i - loff[b])] = pay[i];
    }
}

// ====== cnt: per-bucket degree histogram -> dinv + hd0 (1024 threads) ======
__global__ __launch_bounds__(1024) void k_cnt1F(
        const u32* __restrict__ bkt, const int* __restrict__ cur,
        const int* __restrict__ x, const float* __restrict__ emb,
        float* __restrict__ dinv, float4* __restrict__ hd0, int nN) {
    __shared__ int h[256];
    int t = threadIdx.x, b = blockIdx.x;
    if (t < 256) h[t] = 0;
    __syncthreads();
    int base = b << 14;
    int end = base + cur[b];
    int vend = base + ((end - base) & ~3);   // base 16B-aligned
    for (int i = base + t * 4; i < vend; i += 1024 * 4) {
        uint4 v = *(const uint4*)&bkt[i];
        atomicAdd(&h[v.x >> 17], 1);
        atomicAdd(&h[v.y >> 17], 1);
        atomicAdd(&h[v.z >> 17], 1);
        atomicAdd(&h[v.w >> 17], 1);
    }
    if (vend + t < end) atomicAdd(&h[bkt[vend + t] >> 17], 1);
    __syncthreads();
    if (t < 256) {
        int d = b * 256 + t;
        if (d < nN) {
            float di = rsqrtf((float)h[t] + 1.0f);
            dinv[d] = di;
            int xi = x[d] * 3;
            hd0[d] = make_float4(emb[xi] * di, emb[xi + 1] * di,
                                 emb[xi + 2] * di, 0.f);
        }
    }
}

// ====== aggI: fixed-point LDS accumulation (int atomics only), ASPLIT=8 ====
__global__ __launch_bounds__(256) void k_aggIF(
        const u32* __restrict__ bkt, const int* __restrict__ cur,
        const float4* __restrict__ tab, float* __restrict__ pacc,
        float scale, float inv_scale) {
    __shared__ int acc[768];
    int t = threadIdx.x;
    int blk = blockIdx.x, b = blk >> 3, s = blk & 7;
    int base = b << 14;
    int sz = cur[b];
    int chunk = (sz + ASPLIT - 1) / ASPLIT;
    int st = min(base + s * chunk, base + sz);
    int en = min(st + chunk, base + sz);
    acc[t] = 0; acc[t + 256] = 0; acc[t + 512] = 0;
    __syncthreads();
    int a0 = min((st + 3) & ~3, en);
    if (st + t < a0) {
        u32 v = bkt[st + t];
        float4 h = tab[v & 0x1FFFFu];
        int bin = (int)(v >> 17) * 3;
        atomicAdd(&acc[bin + 0], __float2int_rn(h.x * scale));
        atomicAdd(&acc[bin + 1], __float2int_rn(h.y * scale));
        atomicAdd(&acc[bin + 2], __float2int_rn(h.z * scale));
    }
    int vend = a0 + ((en - a0) & ~3);
    for (int i = a0 + t * 4; i < vend; i += 256 * 4) {
        uint4 v = *(const uint4*)&bkt[i];
        float4 h0 = tab[v.x & 0x1FFFFu];
        float4 h1 = tab[v.y & 0x1FFFFu];
        float4 h2 = tab[v.z & 0x1FFFFu];
        float4 h3 = tab[v.w & 0x1FFFFu];
        int b0 = (int)(v.x >> 17) * 3, b1 = (int)(v.y >> 17) * 3;
        int b2 = (int)(v.z >> 17) * 3, b3 = (int)(v.w >> 17) * 3;
        atomicAdd(&acc[b0 + 0], __float2int_rn(h0.x * scale));
        atomicAdd(&acc[b0 + 1], __float2int_rn(h0.y * scale));
        atomicAdd(&acc[b0 + 2], __float2int_rn(h0.z * scale));
        atomicAdd(&acc[b1 + 0], __float2int_rn(h1.x * scale));
        atomicAdd(&acc[b1 + 1], __float2int_rn(h1.y * scale));
        atomicAdd(&acc[b1 + 2], __float2int_rn(h1.z * scale));
        atomicAdd(&acc[b2 + 0], __float2int_rn(h2.x * scale));
        atomicAdd(&acc[b2 + 1], __float2int_rn(h2.y * scale));
        atomicAdd(&acc[b2 + 2], __float2int_rn(h2.z * scale));
        atomicAdd(&acc[b3 + 0], __float2int_rn(h3.x * scale));
        atomicAdd(&acc[b3 + 1], __float2int_rn(h3.y * scale));
        atomicAdd(&acc[b3 + 2], __float2int_rn(h3.z * scale));
    }
    if (vend + t < en) {
        u32 v = bkt[vend + t];
        float4 h = tab[v & 0x1FFFFu];
        int bin = (int)(v >> 17) * 3;
        atomicAdd(&acc[bin + 0], __float2int_rn(h.x * scale));
        atomicAdd(&acc[bin + 1], __float2int_rn(h.y * scale));
        atomicAdd(&acc[bin + 2], __float2int_rn(h.z * scale));
    }
    __syncthreads();
    float* p = pacc + (size_t)blk * 768;
    p[t]       = (float)acc[t * 3 + 0] * inv_scale;
    p[t + 256] = (float)acc[t * 3 + 1] * inv_scale;
    p[t + 512] = (float)acc[t * 3 + 2] * inv_scale;
}

// ====== fin1: combine partials + self, chain @W1->leaky->@W2, *dinv ========
__global__ void k_fin1(const float* __restrict__ pacc, const float* __restrict__ dinv,
                       const float4* __restrict__ hd0,
                       const float* __restrict__ W1, const float* __restrict__ b1,
                       const float* __restrict__ W2,
                       float4* __restrict__ hd2, int nN) {
    int d = blockIdx.x * blockDim.x + threadIdx.x;
    if (d >= nN) return;
    int b = d >> 8, q = d & 255;
    float s0 = 0.f, s1 = 0.f, s2 = 0.f;
#pragma unroll
    for (int s = 0; s < ASPLIT; ++s) {
        const float* p = pacc + (size_t)(b * ASPLIT + s) * 768;
        s0 += p[q]; s1 += p[q + 256]; s2 += p[q + 512];
    }
    float di = dinv[d];
    float4 self = hd0[d];
    float a0 = di * (s0 + self.x);
    float a1 = di * (s1 + self.y);
    float a2 = di * (s2 + self.z);
    float o0 = 0.f, o1 = 0.f, o2 = 0.f;
#pragma unroll
    for (int k = 0; k < 16; ++k) {
        float p = leaky(a0 * W1[k] + a1 * W1[16 + k] + a2 * W1[32 + k] + b1[k]);
        o0 += p * W2[k * 3 + 0];
        o1 += p * W2[k * 3 + 1];
        o2 += p * W2[k * 3 + 2];
    }
    hd2[d] = make_float4(o0 * di, o1 * di, o2 * di, 0.f);
}

// ====== fin2 ===============================================================
__global__ void k_fin2(const float* __restrict__ pacc, const float* __restrict__ dinv,
                       const float4* __restrict__ hd2, const float* __restrict__ b2,
                       float4* __restrict__ h2, int nN) {
    int d = blockIdx.x * blockDim.x + threadIdx.x;
    if (d >= nN) return;
    int b = d >> 8, q = d & 255;
    float s0 = 0.f, s1 = 0.f, s2 = 0.f;
#pragma unroll
    for (int s = 0; s < ASPLIT; ++s) {
        const float* p = pacc + (size_t)(b * ASPLIT + s) * 768;
        s0 += p[q]; s1 += p[q + 256]; s2 += p[q + 512];
    }
    float di = dinv[d];
    float4 self = hd2[d];
    h2[d] = make_float4(leaky(di * (s0 + self.x) + b2[0]),
                        leaky(di * (s1 + self.y) + b2[1]),
                        leaky(di * (s2 + self.z) + b2[2]), 0.f);
}

// ================= per-match MLP: 4 matches per thread =====================
__global__ __launch_bounds__(256) void k_mlp4v(
        const int* __restrict__ home, const int* __restrict__ away,
        const float4* __restrict__ h2,
        const float* __restrict__ lw1, const float* __restrict__ lb1,
        const float* __restrict__ lw2, const float* __restrict__ lb2,
        const float* __restrict__ lw3, const float* __restrict__ lb3,
        float* __restrict__ out, int nM) {
    __shared__ float s[235];
    int t = threadIdx.x;
    if (t < 96)       s[t] = lw1[t];
    else if (t < 112) s[t] = lb1[t - 96];
    else if (t < 208) s[t] = lw2[t - 112];
    else if (t < 214) s[t] = lb2[t - 208];
    else if (t < 232) s[t] = lw3[t - 214];
    else if (t < 235) s[t] = lb3[t - 232];
    __syncthreads();
    const float* sw1 = s;        const float* sb1 = s + 96;
    const float* sw2 = s + 112;  const float* sb2 = s + 208;
    const float* sw3 = s + 214;  const float* sb3 = s + 232;
    int i = blockIdx.x * blockDim.x + threadIdx.x;
    int m0 = i * 4;
    if (m0 >= nM) return;
    float res[12];
    int nq = min(4, nM - m0);
    int hidx[4], aidx[4];
    if (nq == 4) {
        int4 hv = *(const int4*)&home[m0];
        int4 av = *(const int4*)&away[m0];
        hidx[0] = hv.x; hidx[1] = hv.y; hidx[2] = hv.z; hidx[3] = hv.w;
        aidx[0] = av.x; aidx[1] = av.y; aidx[2] = av.z; aidx[3] = av.w;
    } else {
        for (int j = 0; j < nq; ++j) { hidx[j] = home[m0 + j]; aidx[j] = away[m0 + j]; }
    }
    for (int j = 0; j < nq; ++j) {
        float4 zh = h2[hidx[j]];
        float4 za = h2[aidx[j]];
        float z[6] = {zh.x, zh.y, zh.z, za.x, za.y, za.z};
        float t1[16];
#pragma unroll
        for (int k = 0; k < 16; ++k) {
            float p = sb1[k];
#pragma unroll
            for (int q = 0; q < 6; ++q) p += z[q] * sw1[q * 16 + k];
            t1[k] = leaky(p);
        }
        float t2[6];
#pragma unroll
        for (int k = 0; k < 6; ++k) {
            float p = sb2[k];
#pragma unroll
            for (int q = 0; q < 16; ++q) p += t1[q] * sw2[q * 6 + k];
            t2[k] = leaky(p);
        }
#pragma unroll
        for (int k = 0; k < 3; ++k) {
            float p = sb3[k];
#pragma unroll
            for (int q = 0; q < 6; ++q) p += t2[q] * sw3[q * 3 + k];
            res[j * 3 + k] = leaky(p);
        }
    }
    if (nq == 4) {
        float4* o4 = (float4*)&out[m0 * 3];
        o4[0] = make_float4(res[0], res[1], res[2], res[3]);
        o4[1] = make_float4(res[4], res[5], res[6], res[7]);
        o4[2] = make_float4(res[8], res[9], res[10], res[11]);
    } else {
        for (int j = 0; j < nq * 3; ++j) out[m0 * 3 + j] = res[j];
    }
}

// ================= tiny fallback (float-atomic push) =======================
__global__ void f_deg(const int* __restrict__ dst, float* __restrict__ deg, int nE) {
    int e = blockIdx.x * blockDim.x + threadIdx.x;
    if (e < nE) atomicAdd(&deg[dst[e]], 1.0f);
}
__global__ void f_hd0(const int* __restrict__ x, const float* __restrict__ emb,
                      float* __restrict__ dinv, float4* __restrict__ hd0, int nN) {
    int i = blockIdx.x * blockDim.x + threadIdx.x;
    if (i >= nN) return;
    float di = rsqrtf(dinv[i] + 1.0f);
    dinv[i] = di;
    int xi = x[i] * 3;
    hd0[i] = make_float4(emb[xi] * di, emb[xi + 1] * di, emb[xi + 2] * di, 0.f);
}
__global__ void f_scatter(const int* __restrict__ src, const int* __restrict__ dst,
                          const float4* __restrict__ tab, float* __restrict__ agg, int nE) {
    int e = blockIdx.x * blockDim.x + threadIdx.x;
    if (e >= nE) return;
    int s = src[e], d = dst[e];
    float4 v = tab[s];
    atomicAdd(&agg[d * 3 + 0], v.x);
    atomicAdd(&agg[d * 3 + 1], v.y);
    atomicAdd(&agg[d * 3 + 2], v.z);
}
__global__ void f_fin1(const float* __restrict__ agg, const float* __restrict__ dinv,
                       const float4* __restrict__ hd0,
                       const float* __restrict__ W1, const float* __restrict__ b1,
                       const float* __restrict__ W2, float4* __restrict__ hd2, int nN) {
    int d = blockIdx.x * blockDim.x + threadIdx.x;
    if (d >= nN) return;
    float di = dinv[d];
    float4 self = hd0[d];
    float a0 = di * (agg[d * 3 + 0] + self.x);
    float a1 = di * (agg[d * 3 + 1] + self.y);
    float a2 = di * (agg[d * 3 + 2] + self.z);
    float o0 = 0.f, o1 = 0.f, o2 = 0.f;
#pragma unroll
    for (int k = 0; k < 16; ++k) {
        float p = leaky(a0 * W1[k] + a1 * W1[16 + k] + a2 * W1[32 + k] + b1[k]);
        o0 += p * W2[k * 3 + 0];
        o1 += p * W2[k * 3 + 1];
        o2 += p * W2[k * 3 + 2];
    }
    hd2[d] = make_float4(o0 * di, o1 * di, o2 * di, 0.f);
}
__global__ void f_fin2(const float* __restrict__ agg, const float* __restrict__ dinv,
                       const float4* __restrict__ hd2, const float* __restrict__ b2,
                       float4* __restrict__ h2, int nN) {
    int d = blockIdx.x * blockDim.x + threadIdx.x;
    if (d >= nN) return;
    float di = dinv[d];
    float4 self = hd2[d];
    h2[d] = make_float4(leaky(di * (agg[d * 3 + 0] + self.x) + b2[0]),
                        leaky(di * (agg[d * 3 + 1] + self.y) + b2[1]),
                        leaky(di * (agg[d * 3 + 2] + self.z) + b2[2]), 0.f);
}

// ================= launch =================
extern "C" void kernel_launch(void* const* d_in, const int* in_sizes, int n_in,
                              void* d_out, int out_size, void* d_ws, size_t ws_size,
                              hipStream_t stream) {
    const int*   x    = (const int*)d_in[0];
    const int*   ei   = (const int*)d_in[1];
    const int*   home = (const int*)d_in[2];
    const int*   away = (const int*)d_in[3];
    const float* emb  = (const float*)d_in[4];
    const float* W1   = (const float*)d_in[5];
    const float* b1   = (const float*)d_in[6];
    const float* W2   = (const float*)d_in[7];
    const float* b2   = (const float*)d_in[8];
    const float* lw1  = (const float*)d_in[9];
    const float* lb1  = (const float*)d_in[10];
    const float* lw2  = (const float*)d_in[11];
    const float* lb2  = (const float*)d_in[12];
    const float* lw3  = (const float*)d_in[13];
    const float* lb3  = (const float*)d_in[14];
    float* out = (float*)d_out;

    const int nN = in_sizes[0];       // 100000
    const int nE = in_sizes[1] / 2;   // 5M
    const int nM = in_sizes[2];       // 1M
    const int* src = ei;
    const int* dst = ei + nE;
    const int B = 256;

    const int nb1 = (nE + P1_CHUNK - 1) / P1_CHUNK;
    const size_t paccN = (size_t)NBK * ASPLIT * 768;        // floats
    const size_t bktN = (size_t)NBK * CAPB;                 // u32 (33.5 MB)

    size_t need = (size_t)3 * nN * 16 + bktN * 4 + paccN * 4 +
                  (size_t)nN * 4 + NBK * 4;

    // capacity: per-bucket mean = nE*256/nN (uniform dst over nN nodes)
    double mean_b = (double)nE * 256.0 / (double)nN;
    double sig_b = sqrt(mean_b);
    bool cap_ok = (mean_b + 10.0 * sig_b) < (double)CAPB;

    if (nN <= NBK * 256 && ws_size >= need && cap_ok) {
        char* w = (char*)d_ws;
        float4* hd0 = (float4*)w;                 w += (size_t)nN * 16;
        float4* hd2 = (float4*)w;                 w += (size_t)nN * 16;
        float4* h2  = (float4*)w;                 w += (size_t)nN * 16;
        u32* bkt  = (u32*)w;                      w += bktN * 4;
        float* pacc = (float*)w;                  w += paccN * 4;
        float* dinv = (float*)w;                  w += (size_t)nN * 4;
        int* cur  = (int*)w;

        hipMemsetAsync(cur, 0, NBK * sizeof(int), stream);
        k_p1scatterA<<<nb1, P1T, 0, stream>>>(src, dst, cur, bkt, nE);
        k_cnt1F<<<NBK, 1024, 0, stream>>>(bkt, cur, x, emb, dinv, hd0, nN);
        k_aggIF<<<NBK * ASPLIT, 256, 0, stream>>>(bkt, cur, hd0, pacc,
                                                  S1F, 1.0f / S1F);
        k_fin1<<<(nN + B - 1) / B, B, 0, stream>>>(pacc, dinv, hd0, W1, b1, W2,
                                                   hd2, nN);
        k_aggIF<<<NBK * ASPLIT, 256, 0, stream>>>(bkt, cur, hd2, pacc,
                                                  S2F, 1.0f / S2F);
        k_fin2<<<(nN + B - 1) / B, B, 0, stream>>>(pacc, dinv, hd2, b2, h2, nN);
        int nQuads = (nM + 3) / 4;
        k_mlp4v<<<(nQuads + B - 1) / B, B, 0, stream>>>(home, away, h2,
                                                        lw1, lb1, lw2, lb2,
                                                        lw3, lb3, out, nM);
    } else {
        // compact float-atomic fallback (correct, slower)
        char* w = (char*)d_ws;
        float4* hd0 = (float4*)w;                 w += (size_t)nN * 16;
        float4* hd2 = (float4*)w;                 w += (size_t)nN * 16;
        float4* h2  = (float4*)w;                 w += (size_t)nN * 16;
        float* agg  = (float*)w;                  w += (size_t)3 * nN * 4;
        float* dinv = (float*)w;

        hipMemsetAsync(dinv, 0, (size_t)nN * sizeof(float), stream);
        hipMemsetAsync(agg, 0, (size_t)3 * nN * sizeof(float), stream);
        f_deg<<<(nE + B - 1) / B, B, 0, stream>>>(dst, dinv, nE);
        f_hd0<<<(nN + B - 1) / B, B, 0, stream>>>(x, emb, dinv, hd0, nN);
        f_scatter<<<(nE + B - 1) / B, B, 0, stream>>>(src, dst, hd0, agg, nE);
        f_fin1<<<(nN + B - 1) / B, B, 0, stream>>>(agg, dinv, hd0, W1, b1, W2, hd2, nN);
        hipMemsetAsync(agg, 0, (size_t)3 * nN * sizeof(float), stream);
        f_scatter<<<(nE + B - 1) / B, B, 0, stream>>>(src, dst, hd2, agg, nE);
        f_fin2<<<(nN + B - 1) / B, B, 0, stream>>>(agg, dinv, hd2, b2, h2, nN);
        int nQuads = (nM + 3) / 4;
        k_mlp4v<<<(nQuads + B - 1) / B, B, 0, stream>>>(home, away, h2,
                                                        lw1, lb1, lw2, lb2,
                                                        lw3, lb3, out, nM);
    }
}

// Round 16
// 122.492 us; speedup vs baseline: 1.4403x; 1.0504x over previous
//
#include <hip/hip_runtime.h>

typedef unsigned int u32;
typedef unsigned char u8;

static __device__ __forceinline__ float leaky(float v) {
    return v >= 0.0f ? v : 0.01f * v;
}

#define P1_CHUNK 8192
#define P1T 1024           // scatter block threads (16 waves; 2 blocks/CU)
#define NBK 512            // buckets = dst>>8  (requires nN <= 131072)
#define CAPB 16384         // per-bucket capacity; mean load nE*256/nN = 12800
#define S1F 8388608.0f     // 2^23 fixed-point scale, layer 1
#define S2F 2097152.0f     // 2^21 fixed-point scale, layer 2

// ====== scatter: block reservation, 8-wave shuffle scan, u8 bucket tag =====
__global__ __launch_bounds__(1024) void k_p1scatterA(
        const int* __restrict__ src, const int* __restrict__ dst,
        int* __restrict__ cur, u32* __restrict__ bkt, int nE) {
    __shared__ int sc[NBK];
    __shared__ int loff[NBK];
    __shared__ int gb[NBK];
    __shared__ int lcur[NBK];
    __shared__ int wsum[8];
    __shared__ u32 pay[P1_CHUNK];
    __shared__ u8 bb[P1_CHUNK];     // low 8 bits of bucket; bit8 = (i >= loff[256])
    int t = threadIdx.x;
    if (t < NBK) sc[t] = 0;
    __syncthreads();
    int base = blockIdx.x * P1_CHUNK;
    int lim = min(P1_CHUNK, nE - base);
    if (lim == P1_CHUNK) {
        const int4* p = (const int4*)(dst + base);
        for (int i = t; i < P1_CHUNK / 4; i += P1T) {
            int4 v = p[i];
            atomicAdd(&sc[v.x >> 8], 1);
            atomicAdd(&sc[v.y >> 8], 1);
            atomicAdd(&sc[v.z >> 8], 1);
            atomicAdd(&sc[v.w >> 8], 1);
        }
    } else {
        for (int i = t; i < lim; i += P1T)
            atomicAdd(&sc[dst[base + i] >> 8], 1);
    }
    __syncthreads();
    if (t < NBK) {
        int c = sc[t];
        int lane = t & 63;
        int incl = c;
#pragma unroll
        for (int o = 1; o < 64; o <<= 1) {
            int xv = __shfl_up(incl, o);
            if (lane >= o) incl += xv;
        }
        if (lane == 63) wsum[t >> 6] = incl;
        sc[t] = incl;                       // per-wave inclusive
    }
    __syncthreads();
    if (t == 0) {
        int run = 0;
#pragma unroll
        for (int k = 0; k < 8; ++k) { int v = wsum[k]; wsum[k] = run; run += v; }
    }
    __syncthreads();
    if (t < NBK) {
        int inclw = sc[t];
        int prev = (t & 63) ? sc[t - 1] : 0;
        int c = inclw - prev;
        int excl = prev + wsum[t >> 6];
        loff[t] = excl;
        lcur[t] = excl;
        gb[t] = (t << 14) + ((c > 0) ? atomicAdd(&cur[t], c) : 0);
    }
    __syncthreads();
    int loff256 = loff[256];
    int n4 = lim >> 2;
    const int4* d4p = (const int4*)(dst + base);
    const int4* s4p = (const int4*)(src + base);
    for (int i = t; i < n4; i += P1T) {
        int4 d4 = d4p[i];
        int4 s4 = s4p[i];
        int b, r;
        b = d4.x >> 8; r = atomicAdd(&lcur[b], 1);
        pay[r] = (u32)(((d4.x & 255) << 17) | s4.x); bb[r] = (u8)b;
        b = d4.y >> 8; r = atomicAdd(&lcur[b], 1);
        pay[r] = (u32)(((d4.y & 255) << 17) | s4.y); bb[r] = (u8)b;
        b = d4.z >> 8; r = atomicAdd(&lcur[b], 1);
        pay[r] = (u32)(((d4.z & 255) << 17) | s4.z); bb[r] = (u8)b;
        b = d4.w >> 8; r = atomicAdd(&lcur[b], 1);
        pay[r] = (u32)(((d4.w & 255) << 17) | s4.w); bb[r] = (u8)b;
    }
    for (int i = (n4 << 2) + t; i < lim; i += P1T) {
        int d = dst[base + i], s = src[base + i];
        int b = d >> 8;
        int r = atomicAdd(&lcur[b], 1);
        pay[r] = (u32)(((d & 255) << 17) | s);
        bb[r] = (u8)b;
    }
    __syncthreads();
    for (int i = t; i < lim; i += P1T) {
        int b = (int)bb[i] | ((i >= loff256) ? 256 : 0);
        bkt[gb[b] + (i - loff[b])] = pay[i];
    }
}

// ====== cnt: per-bucket degree histogram -> dinv + hd0 (1024 threads) ======
__global__ __launch_bounds__(1024) void k_cnt1F(
        const u32* __restrict__ bkt, const int* __restrict__ cur,
        const int* __restrict__ x, const float* __restrict__ emb,
        float* __restrict__ dinv, float4* __restrict__ hd0, int nN) {
    __shared__ int h[256];
    int t = threadIdx.x, b = blockIdx.x;
    if (t < 256) h[t] = 0;
    __syncthreads();
    int base = b << 14;
    int end = base + cur[b];
    int vend = base + ((end - base) & ~3);   // base 16B-aligned
    for (int i = base + t * 4; i < vend; i += 1024 * 4) {
        uint4 v = *(const uint4*)&bkt[i];
        atomicAdd(&h[v.x >> 17], 1);
        atomicAdd(&h[v.y >> 17], 1);
        atomicAdd(&h[v.z >> 17], 1);
        atomicAdd(&h[v.w >> 17], 1);
    }
    if (vend + t < end) atomicAdd(&h[bkt[vend + t] >> 17], 1);
    __syncthreads();
    if (t < 256) {
        int d = b * 256 + t;
        if (d < nN) {
            float di = rsqrtf((float)h[t] + 1.0f);
            dinv[d] = di;
            int xi = x[d] * 3;
            hd0[d] = make_float4(emb[xi] * di, emb[xi + 1] * di,
                                 emb[xi + 2] * di, 0.f);
        }
    }
}

// ====== aggF1: whole-bucket fixed-point agg + inline fin1 -> hd2 ===========
__global__ __launch_bounds__(1024) void k_aggF1(
        const u32* __restrict__ bkt, const int* __restrict__ cur,
        const float4* __restrict__ hd0, const float* __restrict__ dinv,
        const float* __restrict__ W1, const float* __restrict__ b1,
        const float* __restrict__ W2,
        float4* __restrict__ hd2, int nN) {
    __shared__ int acc[768];
    int t = threadIdx.x, b = blockIdx.x;
    if (t < 768) acc[t] = 0;
    __syncthreads();
    int base = b << 14;
    int end = base + cur[b];
    int vend = base + ((end - base) & ~3);
    for (int i = base + t * 4; i < vend; i += 1024 * 4) {
        uint4 v = *(const uint4*)&bkt[i];
        float4 h0 = hd0[v.x & 0x1FFFFu];
        float4 h1 = hd0[v.y & 0x1FFFFu];
        float4 h2v = hd0[v.z & 0x1FFFFu];
        float4 h3 = hd0[v.w & 0x1FFFFu];
        int b0 = (int)(v.x >> 17) * 3, b1i = (int)(v.y >> 17) * 3;
        int b2i = (int)(v.z >> 17) * 3, b3 = (int)(v.w >> 17) * 3;
        atomicAdd(&acc[b0 + 0], __float2int_rn(h0.x * S1F));
        atomicAdd(&acc[b0 + 1], __float2int_rn(h0.y * S1F));
        atomicAdd(&acc[b0 + 2], __float2int_rn(h0.z * S1F));
        atomicAdd(&acc[b1i + 0], __float2int_rn(h1.x * S1F));
        atomicAdd(&acc[b1i + 1], __float2int_rn(h1.y * S1F));
        atomicAdd(&acc[b1i + 2], __float2int_rn(h1.z * S1F));
        atomicAdd(&acc[b2i + 0], __float2int_rn(h2v.x * S1F));
        atomicAdd(&acc[b2i + 1], __float2int_rn(h2v.y * S1F));
        atomicAdd(&acc[b2i + 2], __float2int_rn(h2v.z * S1F));
        atomicAdd(&acc[b3 + 0], __float2int_rn(h3.x * S1F));
        atomicAdd(&acc[b3 + 1], __float2int_rn(h3.y * S1F));
        atomicAdd(&acc[b3 + 2], __float2int_rn(h3.z * S1F));
    }
    if (vend + t < end) {
        u32 v = bkt[vend + t];
        float4 h = hd0[v & 0x1FFFFu];
        int bin = (int)(v >> 17) * 3;
        atomicAdd(&acc[bin + 0], __float2int_rn(h.x * S1F));
        atomicAdd(&acc[bin + 1], __float2int_rn(h.y * S1F));
        atomicAdd(&acc[bin + 2], __float2int_rn(h.z * S1F));
    }
    __syncthreads();
    if (t < 256) {
        int d = b * 256 + t;
        if (d < nN) {
            float s0 = (float)acc[t * 3 + 0] * (1.0f / S1F);
            float s1 = (float)acc[t * 3 + 1] * (1.0f / S1F);
            float s2 = (float)acc[t * 3 + 2] * (1.0f / S1F);
            float di = dinv[d];
            float4 self = hd0[d];
            float a0 = di * (s0 + self.x);
            float a1 = di * (s1 + self.y);
            float a2 = di * (s2 + self.z);
            float o0 = 0.f, o1 = 0.f, o2 = 0.f;
#pragma unroll
            for (int k = 0; k < 16; ++k) {
                float p = leaky(a0 * W1[k] + a1 * W1[16 + k] + a2 * W1[32 + k] + b1[k]);
                o0 += p * W2[k * 3 + 0];
                o1 += p * W2[k * 3 + 1];
                o2 += p * W2[k * 3 + 2];
            }
            hd2[d] = make_float4(o0 * di, o1 * di, o2 * di, 0.f);
        }
    }
}

// ====== aggF2: whole-bucket fixed-point agg + inline fin2 -> h2 ============
__global__ __launch_bounds__(1024) void k_aggF2(
        const u32* __restrict__ bkt, const int* __restrict__ cur,
        const float4* __restrict__ hd2, const float* __restrict__ dinv,
        const float* __restrict__ b2,
        float4* __restrict__ h2, int nN) {
    __shared__ int acc[768];
    int t = threadIdx.x, b = blockIdx.x;
    if (t < 768) acc[t] = 0;
    __syncthreads();
    int base = b << 14;
    int end = base + cur[b];
    int vend = base + ((end - base) & ~3);
    for (int i = base + t * 4; i < vend; i += 1024 * 4) {
        uint4 v = *(const uint4*)&bkt[i];
        float4 h0 = hd2[v.x & 0x1FFFFu];
        float4 h1 = hd2[v.y & 0x1FFFFu];
        float4 h2v = hd2[v.z & 0x1FFFFu];
        float4 h3 = hd2[v.w & 0x1FFFFu];
        int b0 = (int)(v.x >> 17) * 3, b1i = (int)(v.y >> 17) * 3;
        int b2i = (int)(v.z >> 17) * 3, b3 = (int)(v.w >> 17) * 3;
        atomicAdd(&acc[b0 + 0], __float2int_rn(h0.x * S2F));
        atomicAdd(&acc[b0 + 1], __float2int_rn(h0.y * S2F));
        atomicAdd(&acc[b0 + 2], __float2int_rn(h0.z * S2F));
        atomicAdd(&acc[b1i + 0], __float2int_rn(h1.x * S2F));
        atomicAdd(&acc[b1i + 1], __float2int_rn(h1.y * S2F));
        atomicAdd(&acc[b1i + 2], __float2int_rn(h1.z * S2F));
        atomicAdd(&acc[b2i + 0], __float2int_rn(h2v.x * S2F));
        atomicAdd(&acc[b2i + 1], __float2int_rn(h2v.y * S2F));
        atomicAdd(&acc[b2i + 2], __float2int_rn(h2v.z * S2F));
        atomicAdd(&acc[b3 + 0], __float2int_rn(h3.x * S2F));
        atomicAdd(&acc[b3 + 1], __float2int_rn(h3.y * S2F));
        atomicAdd(&acc[b3 + 2], __float2int_rn(h3.z * S2F));
    }
    if (vend + t < end) {
        u32 v = bkt[vend + t];
        float4 h = hd2[v & 0x1FFFFu];
        int bin = (int)(v >> 17) * 3;
        atomicAdd(&acc[bin + 0], __float2int_rn(h.x * S2F));
        atomicAdd(&acc[bin + 1], __float2int_rn(h.y * S2F));
        atomicAdd(&acc[bin + 2], __float2int_rn(h.z * S2F));
    }
    __syncthreads();
    if (t < 256) {
        int d = b * 256 + t;
        if (d < nN) {
            float s0 = (float)acc[t * 3 + 0] * (1.0f / S2F);
            float s1 = (float)acc[t * 3 + 1] * (1.0f / S2F);
            float s2 = (float)acc[t * 3 + 2] * (1.0f / S2F);
            float di = dinv[d];
            float4 self = hd2[d];
            h2[d] = make_float4(leaky(di * (s0 + self.x) + b2[0]),
                                leaky(di * (s1 + self.y) + b2[1]),
                                leaky(di * (s2 + self.z) + b2[2]), 0.f);
        }
    }
}

// ================= per-match MLP: 4 matches per thread =====================
__global__ __launch_bounds__(256) void k_mlp4v(
        const int* __restrict__ home, const int* __restrict__ away,
        const float4* __restrict__ h2,
        const float* __restrict__ lw1, const float* __restrict__ lb1,
        const float* __restrict__ lw2, const float* __restrict__ lb2,
        const float* __restrict__ lw3, const float* __restrict__ lb3,
        float* __restrict__ out, int nM) {
    __shared__ float s[235];
    int t = threadIdx.x;
    if (t < 96)       s[t] = lw1[t];
    else if (t < 112) s[t] = lb1[t - 96];
    else if (t < 208) s[t] = lw2[t - 112];
    else if (t < 214) s[t] = lb2[t - 208];
    else if (t < 232) s[t] = lw3[t - 214];
    else if (t < 235) s[t] = lb3[t - 232];
    __syncthreads();
    const float* sw1 = s;        const float* sb1 = s + 96;
    const float* sw2 = s + 112;  const float* sb2 = s + 208;
    const float* sw3 = s + 214;  const float* sb3 = s + 232;
    int i = blockIdx.x * blockDim.x + threadIdx.x;
    int m0 = i * 4;
    if (m0 >= nM) return;
    float res[12];
    int nq = min(4, nM - m0);
    int hidx[4], aidx[4];
    if (nq == 4) {
        int4 hv = *(const int4*)&home[m0];
        int4 av = *(const int4*)&away[m0];
        hidx[0] = hv.x; hidx[1] = hv.y; hidx[2] = hv.z; hidx[3] = hv.w;
        aidx[0] = av.x; aidx[1] = av.y; aidx[2] = av.z; aidx[3] = av.w;
    } else {
        for (int j = 0; j < nq; ++j) { hidx[j] = home[m0 + j]; aidx[j] = away[m0 + j]; }
    }
    for (int j = 0; j < nq; ++j) {
        float4 zh = h2[hidx[j]];
        float4 za = h2[aidx[j]];
        float z[6] = {zh.x, zh.y, zh.z, za.x, za.y, za.z};
        float t1[16];
#pragma unroll
        for (int k = 0; k < 16; ++k) {
            float p = sb1[k];
#pragma unroll
            for (int q = 0; q < 6; ++q) p += z[q] * sw1[q * 16 + k];
            t1[k] = leaky(p);
        }
        float t2[6];
#pragma unroll
        for (int k = 0; k < 6; ++k) {
            float p = sb2[k];
#pragma unroll
            for (int q = 0; q < 16; ++q) p += t1[q] * sw2[q * 6 + k];
            t2[k] = leaky(p);
        }
#pragma unroll
        for (int k = 0; k < 3; ++k) {
            float p = sb3[k];
#pragma unroll
            for (int q = 0; q < 6; ++q) p += t2[q] * sw3[q * 3 + k];
            res[j * 3 + k] = leaky(p);
        }
    }
    if (nq == 4) {
        float4* o4 = (float4*)&out[m0 * 3];
        o4[0] = make_float4(res[0], res[1], res[2], res[3]);
        o4[1] = make_float4(res[4], res[5], res[6], res[7]);
        o4[2] = make_float4(res[8], res[9], res[10], res[11]);
    } else {
        for (int j = 0; j < nq * 3; ++j) out[m0 * 3 + j] = res[j];
    }
}

// ================= tiny fallback (float-atomic push) =======================
__global__ void f_deg(const int* __restrict__ dst, float* __restrict__ deg, int nE) {
    int e = blockIdx.x * blockDim.x + threadIdx.x;
    if (e < nE) atomicAdd(&deg[dst[e]], 1.0f);
}
__global__ void f_hd0(const int* __restrict__ x, const float* __restrict__ emb,
                      float* __restrict__ dinv, float4* __restrict__ hd0, int nN) {
    int i = blockIdx.x * blockDim.x + threadIdx.x;
    if (i >= nN) return;
    float di = rsqrtf(dinv[i] + 1.0f);
    dinv[i] = di;
    int xi = x[i] * 3;
    hd0[i] = make_float4(emb[xi] * di, emb[xi + 1] * di, emb[xi + 2] * di, 0.f);
}
__global__ void f_scatter(const int* __restrict__ src, const int* __restrict__ dst,
                          const float4* __restrict__ tab, float* __restrict__ agg, int nE) {
    int e = blockIdx.x * blockDim.x + threadIdx.x;
    if (e >= nE) return;
    int s = src[e], d = dst[e];
    float4 v = tab[s];
    atomicAdd(&agg[d * 3 + 0], v.x);
    atomicAdd(&agg[d * 3 + 1], v.y);
    atomicAdd(&agg[d * 3 + 2], v.z);
}
__global__ void f_fin1(const float* __restrict__ agg, const float* __restrict__ dinv,
                       const float4* __restrict__ hd0,
                       const float* __restrict__ W1, const float* __restrict__ b1,
                       const float* __restrict__ W2, float4* __restrict__ hd2, int nN) {
    int d = blockIdx.x * blockDim.x + threadIdx.x;
    if (d >= nN) return;
    float di = dinv[d];
    float4 self = hd0[d];
    float a0 = di * (agg[d * 3 + 0] + self.x);
    float a1 = di * (agg[d * 3 + 1] + self.y);
    float a2 = di * (agg[d * 3 + 2] + self.z);
    float o0 = 0.f, o1 = 0.f, o2 = 0.f;
#pragma unroll
    for (int k = 0; k < 16; ++k) {
        float p = leaky(a0 * W1[k] + a1 * W1[16 + k] + a2 * W1[32 + k] + b1[k]);
        o0 += p * W2[k * 3 + 0];
        o1 += p * W2[k * 3 + 1];
        o2 += p * W2[k * 3 + 2];
    }
    hd2[d] = make_float4(o0 * di, o1 * di, o2 * di, 0.f);
}
__global__ void f_fin2(const float* __restrict__ agg, const float* __restrict__ dinv,
                       const float4* __restrict__ hd2, const float* __restrict__ b2,
                       float4* __restrict__ h2, int nN) {
    int d = blockIdx.x * blockDim.x + threadIdx.x;
    if (d >= nN) return;
    float di = dinv[d];
    float4 self = hd2[d];
    h2[d] = make_float4(leaky(di * (agg[d * 3 + 0] + self.x) + b2[0]),
                        leaky(di * (agg[d * 3 + 1] + self.y) + b2[1]),
                        leaky(di * (agg[d * 3 + 2] + self.z) + b2[2]), 0.f);
}

// ================= launch =================
extern "C" void kernel_launch(void* const* d_in, const int* in_sizes, int n_in,
                              void* d_out, int out_size, void* d_ws, size_t ws_size,
                              hipStream_t stream) {
    const int*   x    = (const int*)d_in[0];
    const int*   ei   = (const int*)d_in[1];
    const int*   home = (const int*)d_in[2];
    const int*   away = (const int*)d_in[3];
    const float* emb  = (const float*)d_in[4];
    const float* W1   = (const float*)d_in[5];
    const float* b1   = (const float*)d_in[6];
    const float* W2   = (const float*)d_in[7];
    const float* b2   = (const float*)d_in[8];
    const float* lw1  = (const float*)d_in[9];
    const float* lb1  = (const float*)d_in[10];
    const float* lw2  = (const float*)d_in[11];
    const float* lb2  = (const float*)d_in[12];
    const float* lw3  = (const float*)d_in[13];
    const float* lb3  = (const float*)d_in[14];
    float* out = (float*)d_out;

    const int nN = in_sizes[0];       // 100000
    const int nE = in_sizes[1] / 2;   // 5M
    const int nM = in_sizes[2];       // 1M
    const int* src = ei;
    const int* dst = ei + nE;
    const int B = 256;

    const int nb1 = (nE + P1_CHUNK - 1) / P1_CHUNK;
    const size_t bktN = (size_t)NBK * CAPB;                 // u32 (33.5 MB)

    size_t need = (size_t)3 * nN * 16 + bktN * 4 + (size_t)nN * 4 + NBK * 4;

    // capacity: per-bucket mean = nE*256/nN (uniform dst over nN nodes)
    double mean_b = (double)nE * 256.0 / (double)nN;
    double sig_b = sqrt(mean_b);
    bool cap_ok = (mean_b + 10.0 * sig_b) < (double)CAPB;

    if (nN <= NBK * 256 && ws_size >= need && cap_ok) {
        char* w = (char*)d_ws;
        float4* hd0 = (float4*)w;                 w += (size_t)nN * 16;
        float4* hd2 = (float4*)w;                 w += (size_t)nN * 16;
        float4* h2  = (float4*)w;                 w += (size_t)nN * 16;
        u32* bkt  = (u32*)w;                      w += bktN * 4;
        float* dinv = (float*)w;                  w += (size_t)nN * 4;
        int* cur  = (int*)w;

        hipMemsetAsync(cur, 0, NBK * sizeof(int), stream);
        k_p1scatterA<<<nb1, P1T, 0, stream>>>(src, dst, cur, bkt, nE);
        k_cnt1F<<<NBK, 1024, 0, stream>>>(bkt, cur, x, emb, dinv, hd0, nN);
        k_aggF1<<<NBK, 1024, 0, stream>>>(bkt, cur, hd0, dinv, W1, b1, W2,
                                          hd2, nN);
        k_aggF2<<<NBK, 1024, 0, stream>>>(bkt, cur, hd2, dinv, b2, h2, nN);
        int nQuads = (nM + 3) / 4;
        k_mlp4v<<<(nQuads + B - 1) / B, B, 0, stream>>>(home, away, h2,
                                                        lw1, lb1, lw2, lb2,
                                                        lw3, lb3, out, nM);
    } else {
        // compact float-atomic fallback (correct, slower)
        char* w = (char*)d_ws;
        float4* hd0 = (float4*)w;                 w += (size_t)nN * 16;
        float4* hd2 = (float4*)w;                 w += (size_t)nN * 16;
        float4* h2  = (float4*)w;                 w += (size_t)nN * 16;
        float* agg  = (float*)w;                  w += (size_t)3 * nN * 4;
        float* dinv = (float*)w;

        hipMemsetAsync(dinv, 0, (size_t)nN * sizeof(float), stream);
        hipMemsetAsync(agg, 0, (size_t)3 * nN * sizeof(float), stream);
        f_deg<<<(nE + B - 1) / B, B, 0, stream>>>(dst, dinv, nE);
        f_hd0<<<(nN + B - 1) / B, B, 0, stream>>>(x, emb, dinv, hd0, nN);
        f_scatter<<<(nE + B - 1) / B, B, 0, stream>>>(src, dst, hd0, agg, nE);
        f_fin1<<<(nN + B - 1) / B, B, 0, stream>>>(agg, dinv, hd0, W1, b1, W2, hd2, nN);
        hipMemsetAsync(agg, 0, (size_t)3 * nN * sizeof(float), stream);
        f_scatter<<<(nE + B - 1) / B, B, 0, stream>>>(src, dst, hd2, agg, nE);
        f_fin2<<<(nN + B - 1) / B, B, 0, stream>>>(agg, dinv, hd2, b2, h2, nN);
        int nQuads = (nM + 3) / 4;
        k_mlp4v<<<(nQuads + B - 1) / B, B, 0, stream>>>(home, away, h2,
                                                        lw1, lb1, lw2, lb2,
                                                        lw3, lb3, out, nM);
    }
}

// Round 17
// 121.603 us; speedup vs baseline: 1.4508x; 1.0073x over previous
//
#include <hip/hip_runtime.h>

typedef unsigned int u32;
typedef unsigned char u8;

static __device__ __forceinline__ float leaky(float v) {
    return v >= 0.0f ? v : 0.01f * v;
}

#define P1_CHUNK 8192
#define P1T 1024           // scatter block threads (16 waves; 2 blocks/CU)
#define NBK 512            // buckets = dst>>8  (requires nN <= 131072)
#define CAPB 16384         // per-bucket capacity; mean load nE*256/nN = 12800
#define S1F 8388608.0f     // 2^23 fixed-point scale, layer 1
#define S2F 2097152.0f     // 2^21 fixed-point scale, layer 2

// ====== scatter: dst register-cached (single global pass), block reservation
__global__ __launch_bounds__(1024) void k_p1scatterA(
        const int* __restrict__ src, const int* __restrict__ dst,
        int* __restrict__ cur, u32* __restrict__ bkt, int nE) {
    __shared__ int sc[NBK];
    __shared__ int loff[NBK];
    __shared__ int gb[NBK];
    __shared__ int lcur[NBK];
    __shared__ int wsum[8];
    __shared__ u32 pay[P1_CHUNK];
    __shared__ u8 bb[P1_CHUNK];     // low 8 bits of bucket; bit8 = (i >= loff[256])
    int t = threadIdx.x;
    if (t < NBK) sc[t] = 0;
    __syncthreads();
    int base = blockIdx.x * P1_CHUNK;
    int lim = min(P1_CHUNK, nE - base);
    bool full = (lim == P1_CHUNK);
    int4 dA, dB;                     // 8 dst values held in registers
    if (full) {
        const int4* d4p = (const int4*)(dst + base);
        dA = d4p[t];
        dB = d4p[t + 1024];
        atomicAdd(&sc[dA.x >> 8], 1);
        atomicAdd(&sc[dA.y >> 8], 1);
        atomicAdd(&sc[dA.z >> 8], 1);
        atomicAdd(&sc[dA.w >> 8], 1);
        atomicAdd(&sc[dB.x >> 8], 1);
        atomicAdd(&sc[dB.y >> 8], 1);
        atomicAdd(&sc[dB.z >> 8], 1);
        atomicAdd(&sc[dB.w >> 8], 1);
    } else {
        for (int i = t; i < lim; i += P1T)
            atomicAdd(&sc[dst[base + i] >> 8], 1);
    }
    __syncthreads();
    if (t < NBK) {
        int c = sc[t];
        int lane = t & 63;
        int incl = c;
#pragma unroll
        for (int o = 1; o < 64; o <<= 1) {
            int xv = __shfl_up(incl, o);
            if (lane >= o) incl += xv;
        }
        if (lane == 63) wsum[t >> 6] = incl;
        sc[t] = incl;                       // per-wave inclusive
    }
    __syncthreads();
    if (t == 0) {
        int run = 0;
#pragma unroll
        for (int k = 0; k < 8; ++k) { int v = wsum[k]; wsum[k] = run; run += v; }
    }
    __syncthreads();
    if (t < NBK) {
        int inclw = sc[t];
        int prev = (t & 63) ? sc[t - 1] : 0;
        int c = inclw - prev;
        int excl = prev + wsum[t >> 6];
        loff[t] = excl;
        lcur[t] = excl;
        gb[t] = (t << 14) + ((c > 0) ? atomicAdd(&cur[t], c) : 0);
    }
    __syncthreads();
    int loff256 = loff[256];
    if (full) {
        const int4* s4p = (const int4*)(src + base);
        int4 sA = s4p[t];
        int4 sB = s4p[t + 1024];
        int b, r;
        b = dA.x >> 8; r = atomicAdd(&lcur[b], 1);
        pay[r] = (u32)(((dA.x & 255) << 17) | sA.x); bb[r] = (u8)b;
        b = dA.y >> 8; r = atomicAdd(&lcur[b], 1);
        pay[r] = (u32)(((dA.y & 255) << 17) | sA.y); bb[r] = (u8)b;
        b = dA.z >> 8; r = atomicAdd(&lcur[b], 1);
        pay[r] = (u32)(((dA.z & 255) << 17) | sA.z); bb[r] = (u8)b;
        b = dA.w >> 8; r = atomicAdd(&lcur[b], 1);
        pay[r] = (u32)(((dA.w & 255) << 17) | sA.w); bb[r] = (u8)b;
        b = dB.x >> 8; r = atomicAdd(&lcur[b], 1);
        pay[r] = (u32)(((dB.x & 255) << 17) | sB.x); bb[r] = (u8)b;
        b = dB.y >> 8; r = atomicAdd(&lcur[b], 1);
        pay[r] = (u32)(((dB.y & 255) << 17) | sB.y); bb[r] = (u8)b;
        b = dB.z >> 8; r = atomicAdd(&lcur[b], 1);
        pay[r] = (u32)(((dB.z & 255) << 17) | sB.z); bb[r] = (u8)b;
        b = dB.w >> 8; r = atomicAdd(&lcur[b], 1);
        pay[r] = (u32)(((dB.w & 255) << 17) | sB.w); bb[r] = (u8)b;
    } else {
        for (int i = t; i < lim; i += P1T) {
            int d = dst[base + i], s = src[base + i];
            int b = d >> 8;
            int r = atomicAdd(&lcur[b], 1);
            pay[r] = (u32)(((d & 255) << 17) | s);
            bb[r] = (u8)b;
        }
    }
    __syncthreads();
    for (int i = t; i < lim; i += P1T) {
        int b = (int)bb[i] | ((i >= loff256) ? 256 : 0);
        bkt[gb[b] + (i - loff[b])] = pay[i];
    }
}

// ====== cnt: per-bucket degree histogram -> dinv + hd0 (1024 threads) ======
__global__ __launch_bounds__(1024) void k_cnt1F(
        const u32* __restrict__ bkt, const int* __restrict__ cur,
        const int* __restrict__ x, const float* __restrict__ emb,
        float* __restrict__ dinv, float4* __restrict__ hd0, int nN) {
    __shared__ int h[256];
    int t = threadIdx.x, b = blockIdx.x;
    if (t < 256) h[t] = 0;
    __syncthreads();
    int base = b << 14;
    int end = base + cur[b];
    int vend = base + ((end - base) & ~3);   // base 16B-aligned
    for (int i = base + t * 4; i < vend; i += 1024 * 4) {
        uint4 v = *(const uint4*)&bkt[i];
        atomicAdd(&h[v.x >> 17], 1);
        atomicAdd(&h[v.y >> 17], 1);
        atomicAdd(&h[v.z >> 17], 1);
        atomicAdd(&h[v.w >> 17], 1);
    }
    if (vend + t < end) atomicAdd(&h[bkt[vend + t] >> 17], 1);
    __syncthreads();
    if (t < 256) {
        int d = b * 256 + t;
        if (d < nN) {
            float di = rsqrtf((float)h[t] + 1.0f);
            dinv[d] = di;
            int xi = x[d] * 3;
            hd0[d] = make_float4(emb[xi] * di, emb[xi + 1] * di,
                                 emb[xi + 2] * di, 0.f);
        }
    }
}

// ====== aggF1: whole-bucket fixed-point agg + inline fin1 -> hd2 ===========
__global__ __launch_bounds__(1024) void k_aggF1(
        const u32* __restrict__ bkt, const int* __restrict__ cur,
        const float4* __restrict__ hd0, const float* __restrict__ dinv,
        const float* __restrict__ W1, const float* __restrict__ b1,
        const float* __restrict__ W2,
        float4* __restrict__ hd2, int nN) {
    __shared__ int acc[768];
    int t = threadIdx.x, b = blockIdx.x;
    if (t < 768) acc[t] = 0;
    __syncthreads();
    int base = b << 14;
    int end = base + cur[b];
    int vend = base + ((end - base) & ~3);
    for (int i = base + t * 4; i < vend; i += 1024 * 4) {
        uint4 v = *(const uint4*)&bkt[i];
        float4 h0 = hd0[v.x & 0x1FFFFu];
        float4 h1 = hd0[v.y & 0x1FFFFu];
        float4 h2v = hd0[v.z & 0x1FFFFu];
        float4 h3 = hd0[v.w & 0x1FFFFu];
        int b0 = (int)(v.x >> 17) * 3, b1i = (int)(v.y >> 17) * 3;
        int b2i = (int)(v.z >> 17) * 3, b3 = (int)(v.w >> 17) * 3;
        atomicAdd(&acc[b0 + 0], __float2int_rn(h0.x * S1F));
        atomicAdd(&acc[b0 + 1], __float2int_rn(h0.y * S1F));
        atomicAdd(&acc[b0 + 2], __float2int_rn(h0.z * S1F));
        atomicAdd(&acc[b1i + 0], __float2int_rn(h1.x * S1F));
        atomicAdd(&acc[b1i + 1], __float2int_rn(h1.y * S1F));
        atomicAdd(&acc[b1i + 2], __float2int_rn(h1.z * S1F));
        atomicAdd(&acc[b2i + 0], __float2int_rn(h2v.x * S1F));
        atomicAdd(&acc[b2i + 1], __float2int_rn(h2v.y * S1F));
        atomicAdd(&acc[b2i + 2], __float2int_rn(h2v.z * S1F));
        atomicAdd(&acc[b3 + 0], __float2int_rn(h3.x * S1F));
        atomicAdd(&acc[b3 + 1], __float2int_rn(h3.y * S1F));
        atomicAdd(&acc[b3 + 2], __float2int_rn(h3.z * S1F));
    }
    if (vend + t < end) {
        u32 v = bkt[vend + t];
        float4 h = hd0[v & 0x1FFFFu];
        int bin = (int)(v >> 17) * 3;
        atomicAdd(&acc[bin + 0], __float2int_rn(h.x * S1F));
        atomicAdd(&acc[bin + 1], __float2int_rn(h.y * S1F));
        atomicAdd(&acc[bin + 2], __float2int_rn(h.z * S1F));
    }
    __syncthreads();
    if (t < 256) {
        int d = b * 256 + t;
        if (d < nN) {
            float s0 = (float)acc[t * 3 + 0] * (1.0f / S1F);
            float s1 = (float)acc[t * 3 + 1] * (1.0f / S1F);
            float s2 = (float)acc[t * 3 + 2] * (1.0f / S1F);
            float di = dinv[d];
            float4 self = hd0[d];
            float a0 = di * (s0 + self.x);
            float a1 = di * (s1 + self.y);
            float a2 = di * (s2 + self.z);
            float o0 = 0.f, o1 = 0.f, o2 = 0.f;
#pragma unroll
            for (int k = 0; k < 16; ++k) {
                float p = leaky(a0 * W1[k] + a1 * W1[16 + k] + a2 * W1[32 + k] + b1[k]);
                o0 += p * W2[k * 3 + 0];
                o1 += p * W2[k * 3 + 1];
                o2 += p * W2[k * 3 + 2];
            }
            hd2[d] = make_float4(o0 * di, o1 * di, o2 * di, 0.f);
        }
    }
}

// ====== aggF2: whole-bucket fixed-point agg + inline fin2 -> h2 ============
__global__ __launch_bounds__(1024) void k_aggF2(
        const u32* __restrict__ bkt, const int* __restrict__ cur,
        const float4* __restrict__ hd2, const float* __restrict__ dinv,
        const float* __restrict__ b2,
        float4* __restrict__ h2, int nN) {
    __shared__ int acc[768];
    int t = threadIdx.x, b = blockIdx.x;
    if (t < 768) acc[t] = 0;
    __syncthreads();
    int base = b << 14;
    int end = base + cur[b];
    int vend = base + ((end - base) & ~3);
    for (int i = base + t * 4; i < vend; i += 1024 * 4) {
        uint4 v = *(const uint4*)&bkt[i];
        float4 h0 = hd2[v.x & 0x1FFFFu];
        float4 h1 = hd2[v.y & 0x1FFFFu];
        float4 h2v = hd2[v.z & 0x1FFFFu];
        float4 h3 = hd2[v.w & 0x1FFFFu];
        int b0 = (int)(v.x >> 17) * 3, b1i = (int)(v.y >> 17) * 3;
        int b2i = (int)(v.z >> 17) * 3, b3 = (int)(v.w >> 17) * 3;
        atomicAdd(&acc[b0 + 0], __float2int_rn(h0.x * S2F));
        atomicAdd(&acc[b0 + 1], __float2int_rn(h0.y * S2F));
        atomicAdd(&acc[b0 + 2], __float2int_rn(h0.z * S2F));
        atomicAdd(&acc[b1i + 0], __float2int_rn(h1.x * S2F));
        atomicAdd(&acc[b1i + 1], __float2int_rn(h1.y * S2F));
        atomicAdd(&acc[b1i + 2], __float2int_rn(h1.z * S2F));
        atomicAdd(&acc[b2i + 0], __float2int_rn(h2v.x * S2F));
        atomicAdd(&acc[b2i + 1], __float2int_rn(h2v.y * S2F));
        atomicAdd(&acc[b2i + 2], __float2int_rn(h2v.z * S2F));
        atomicAdd(&acc[b3 + 0], __float2int_rn(h3.x * S2F));
        atomicAdd(&acc[b3 + 1], __float2int_rn(h3.y * S2F));
        atomicAdd(&acc[b3 + 2], __float2int_rn(h3.z * S2F));
    }
    if (vend + t < end) {
        u32 v = bkt[vend + t];
        float4 h = hd2[v & 0x1FFFFu];
        int bin = (int)(v >> 17) * 3;
        atomicAdd(&acc[bin + 0], __float2int_rn(h.x * S2F));
        atomicAdd(&acc[bin + 1], __float2int_rn(h.y * S2F));
        atomicAdd(&acc[bin + 2], __float2int_rn(h.z * S2F));
    }
    __syncthreads();
    if (t < 256) {
        int d = b * 256 + t;
        if (d < nN) {
            float s0 = (float)acc[t * 3 + 0] * (1.0f / S2F);
            float s1 = (float)acc[t * 3 + 1] * (1.0f / S2F);
            float s2 = (float)acc[t * 3 + 2] * (1.0f / S2F);
            float di = dinv[d];
            float4 self = hd2[d];
            h2[d] = make_float4(leaky(di * (s0 + self.x) + b2[0]),
                                leaky(di * (s1 + self.y) + b2[1]),
                                leaky(di * (s2 + self.z) + b2[2]), 0.f);
        }
    }
}

// ================= per-match MLP: 4 matches per thread =====================
__global__ __launch_bounds__(256) void k_mlp4v(
        const int* __restrict__ home, const int* __restrict__ away,
        const float4* __restrict__ h2,
        const float* __restrict__ lw1, const float* __restrict__ lb1,
        const float* __restrict__ lw2, const float* __restrict__ lb2,
        const float* __restrict__ lw3, const float* __restrict__ lb3,
        float* __restrict__ out, int nM) {
    __shared__ float s[235];
    int t = threadIdx.x;
    if (t < 96)       s[t] = lw1[t];
    else if (t < 112) s[t] = lb1[t - 96];
    else if (t < 208) s[t] = lw2[t - 112];
    else if (t < 214) s[t] = lb2[t - 208];
    else if (t < 232) s[t] = lw3[t - 214];
    else if (t < 235) s[t] = lb3[t - 232];
    __syncthreads();
    const float* sw1 = s;        const float* sb1 = s + 96;
    const float* sw2 = s + 112;  const float* sb2 = s + 208;
    const float* sw3 = s + 214;  const float* sb3 = s + 232;
    int i = blockIdx.x * blockDim.x + threadIdx.x;
    int m0 = i * 4;
    if (m0 >= nM) return;
    float res[12];
    int nq = min(4, nM - m0);
    int hidx[4], aidx[4];
    if (nq == 4) {
        int4 hv = *(const int4*)&home[m0];
        int4 av = *(const int4*)&away[m0];
        hidx[0] = hv.x; hidx[1] = hv.y; hidx[2] = hv.z; hidx[3] = hv.w;
        aidx[0] = av.x; aidx[1] = av.y; aidx[2] = av.z; aidx[3] = av.w;
    } else {
        for (int j = 0; j < nq; ++j) { hidx[j] = home[m0 + j]; aidx[j] = away[m0 + j]; }
    }
    for (int j = 0; j < nq; ++j) {
        float4 zh = h2[hidx[j]];
        float4 za = h2[aidx[j]];
        float z[6] = {zh.x, zh.y, zh.z, za.x, za.y, za.z};
        float t1[16];
#pragma unroll
        for (int k = 0; k < 16; ++k) {
            float p = sb1[k];
#pragma unroll
            for (int q = 0; q < 6; ++q) p += z[q] * sw1[q * 16 + k];
            t1[k] = leaky(p);
        }
        float t2[6];
#pragma unroll
        for (int k = 0; k < 6; ++k) {
            float p = sb2[k];
#pragma unroll
            for (int q = 0; q < 16; ++q) p += t1[q] * sw2[q * 6 + k];
            t2[k] = leaky(p);
        }
#pragma unroll
        for (int k = 0; k < 3; ++k) {
            float p = sb3[k];
#pragma unroll
            for (int q = 0; q < 6; ++q) p += t2[q] * sw3[q * 3 + k];
            res[j * 3 + k] = leaky(p);
        }
    }
    if (nq == 4) {
        float4* o4 = (float4*)&out[m0 * 3];
        o4[0] = make_float4(res[0], res[1], res[2], res[3]);
        o4[1] = make_float4(res[4], res[5], res[6], res[7]);
        o4[2] = make_float4(res[8], res[9], res[10], res[11]);
    } else {
        for (int j = 0; j < nq * 3; ++j) out[m0 * 3 + j] = res[j];
    }
}

// ================= tiny fallback (float-atomic push) =======================
__global__ void f_deg(const int* __restrict__ dst, float* __restrict__ deg, int nE) {
    int e = blockIdx.x * blockDim.x + threadIdx.x;
    if (e < nE) atomicAdd(&deg[dst[e]], 1.0f);
}
__global__ void f_hd0(const int* __restrict__ x, const float* __restrict__ emb,
                      float* __restrict__ dinv, float4* __restrict__ hd0, int nN) {
    int i = blockIdx.x * blockDim.x + threadIdx.x;
    if (i >= nN) return;
    float di = rsqrtf(dinv[i] + 1.0f);
    dinv[i] = di;
    int xi = x[i] * 3;
    hd0[i] = make_float4(emb[xi] * di, emb[xi + 1] * di, emb[xi + 2] * di, 0.f);
}
__global__ void f_scatter(const int* __restrict__ src, const int* __restrict__ dst,
                          const float4* __restrict__ tab, float* __restrict__ agg, int nE) {
    int e = blockIdx.x * blockDim.x + threadIdx.x;
    if (e >= nE) return;
    int s = src[e], d = dst[e];
    float4 v = tab[s];
    atomicAdd(&agg[d * 3 + 0], v.x);
    atomicAdd(&agg[d * 3 + 1], v.y);
    atomicAdd(&agg[d * 3 + 2], v.z);
}
__global__ void f_fin1(const float* __restrict__ agg, const float* __restrict__ dinv,
                       const float4* __restrict__ hd0,
                       const float* __restrict__ W1, const float* __restrict__ b1,
                       const float* __restrict__ W2, float4* __restrict__ hd2, int nN) {
    int d = blockIdx.x * blockDim.x + threadIdx.x;
    if (d >= nN) return;
    float di = dinv[d];
    float4 self = hd0[d];
    float a0 = di * (agg[d * 3 + 0] + self.x);
    float a1 = di * (agg[d * 3 + 1] + self.y);
    float a2 = di * (agg[d * 3 + 2] + self.z);
    float o0 = 0.f, o1 = 0.f, o2 = 0.f;
#pragma unroll
    for (int k = 0; k < 16; ++k) {
        float p = leaky(a0 * W1[k] + a1 * W1[16 + k] + a2 * W1[32 + k] + b1[k]);
        o0 += p * W2[k * 3 + 0];
        o1 += p * W2[k * 3 + 1];
        o2 += p * W2[k * 3 + 2];
    }
    hd2[d] = make_float4(o0 * di, o1 * di, o2 * di, 0.f);
}
__global__ void f_fin2(const float* __restrict__ agg, const float* __restrict__ dinv,
                       const float4* __restrict__ hd2, const float* __restrict__ b2,
                       float4* __restrict__ h2, int nN) {
    int d = blockIdx.x * blockDim.x + threadIdx.x;
    if (d >= nN) return;
    float di = dinv[d];
    float4 self = hd2[d];
    h2[d] = make_float4(leaky(di * (agg[d * 3 + 0] + self.x) + b2[0]),
                        leaky(di * (agg[d * 3 + 1] + self.y) + b2[1]),
                        leaky(di * (agg[d * 3 + 2] + self.z) + b2[2]), 0.f);
}

// ================= launch =================
extern "C" void kernel_launch(void* const* d_in, const int* in_sizes, int n_in,
                              void* d_out, int out_size, void* d_ws, size_t ws_size,
                              hipStream_t stream) {
    const int*   x    = (const int*)d_in[0];
    const int*   ei   = (const int*)d_in[1];
    const int*   home = (const int*)d_in[2];
    const int*   away = (const int*)d_in[3];
    const float* emb  = (const float*)d_in[4];
    const float* W1   = (const float*)d_in[5];
    const float* b1   = (const float*)d_in[6];
    const float* W2   = (const float*)d_in[7];
    const float* b2   = (const float*)d_in[8];
    const float* lw1  = (const float*)d_in[9];
    const float* lb1  = (const float*)d_in[10];
    const float* lw2  = (const float*)d_in[11];
    const float* lb2  = (const float*)d_in[12];
    const float* lw3  = (const float*)d_in[13];
    const float* lb3  = (const float*)d_in[14];
    float* out = (float*)d_out;

    const int nN = in_sizes[0];       // 100000
    const int nE = in_sizes[1] / 2;   // 5M
    const int nM = in_sizes[2];       // 1M
    const int* src = ei;
    const int* dst = ei + nE;
    const int B = 256;

    const int nb1 = (nE + P1_CHUNK - 1) / P1_CHUNK;
    const size_t bktN = (size_t)NBK * CAPB;                 // u32 (33.5 MB)

    size_t need = (size_t)3 * nN * 16 + bktN * 4 + (size_t)nN * 4 + NBK * 4;

    // capacity: per-bucket mean = nE*256/nN (uniform dst over nN nodes)
    double mean_b = (double)nE * 256.0 / (double)nN;
    double sig_b = sqrt(mean_b);
    bool cap_ok = (mean_b + 10.0 * sig_b) < (double)CAPB;

    if (nN <= NBK * 256 && ws_size >= need && cap_ok) {
        char* w = (char*)d_ws;
        float4* hd0 = (float4*)w;                 w += (size_t)nN * 16;
        float4* hd2 = (float4*)w;                 w += (size_t)nN * 16;
        float4* h2  = (float4*)w;                 w += (size_t)nN * 16;
        u32* bkt  = (u32*)w;                      w += bktN * 4;
        float* dinv = (float*)w;                  w += (size_t)nN * 4;
        int* cur  = (int*)w;

        hipMemsetAsync(cur, 0, NBK * sizeof(int), stream);
        k_p1scatterA<<<nb1, P1T, 0, stream>>>(src, dst, cur, bkt, nE);
        k_cnt1F<<<NBK, 1024, 0, stream>>>(bkt, cur, x, emb, dinv, hd0, nN);
        k_aggF1<<<NBK, 1024, 0, stream>>>(bkt, cur, hd0, dinv, W1, b1, W2,
                                          hd2, nN);
        k_aggF2<<<NBK, 1024, 0, stream>>>(bkt, cur, hd2, dinv, b2, h2, nN);
        int nQuads = (nM + 3) / 4;
        k_mlp4v<<<(nQuads + B - 1) / B, B, 0, stream>>>(home, away, h2,
                                                        lw1, lb1, lw2, lb2,
                                                        lw3, lb3, out, nM);
    } else {
        // compact float-atomic fallback (correct, slower)
        char* w = (char*)d_ws;
        float4* hd0 = (float4*)w;                 w += (size_t)nN * 16;
        float4* hd2 = (float4*)w;                 w += (size_t)nN * 16;
        float4* h2  = (float4*)w;                 w += (size_t)nN * 16;
        float* agg  = (float*)w;                  w += (size_t)3 * nN * 4;
        float* dinv = (float*)w;

        hipMemsetAsync(dinv, 0, (size_t)nN * sizeof(float), stream);
        hipMemsetAsync(agg, 0, (size_t)3 * nN * sizeof(float), stream);
        f_deg<<<(nE + B - 1) / B, B, 0, stream>>>(dst, dinv, nE);
        f_hd0<<<(nN + B - 1) / B, B, 0, stream>>>(x, emb, dinv, hd0, nN);
        f_scatter<<<(nE + B - 1) / B, B, 0, stream>>>(src, dst, hd0, agg, nE);
        f_fin1<<<(nN + B - 1) / B, B, 0, stream>>>(agg, dinv, hd0, W1, b1, W2, hd2, nN);
        hipMemsetAsync(agg, 0, (size_t)3 * nN * sizeof(float), stream);
        f_scatter<<<(nE + B - 1) / B, B, 0, stream>>>(src, dst, hd2, agg, nE);
        f_fin2<<<(nN + B - 1) / B, B, 0, stream>>>(agg, dinv, hd2, b2, h2, nN);
        int nQuads = (nM + 3) / 4;
        k_mlp4v<<<(nQuads + B - 1) / B, B, 0, stream>>>(home, away, h2,
                                                        lw1, lb1, lw2, lb2,
                                                        lw3, lb3, out, nM);
    }
}